// Round 8
// baseline (252.732 us; speedup 1.0000x reference)
//
#include <hip/hip_runtime.h>
#include <hip/hip_bf16.h>
#include <math.h>

#define N_TOK 4096
#define CA 768
#define CS 384
#define CZ 128
#define NHEAD 16
#define DH 48
#define NQW 32
#define NKW 128
#define NBLK 128

typedef __attribute__((ext_vector_type(8))) short short8;
typedef __attribute__((ext_vector_type(4))) float float4v;
typedef __attribute__((ext_vector_type(4))) unsigned short ushort4v;

__device__ __forceinline__ float sigmoidf_(float x){ return 1.0f/(1.0f+__expf(-x)); }

__device__ __forceinline__ unsigned short f2bf(float x){
  unsigned u = __float_as_uint(x);
  unsigned r = (u + 0x7FFFu + ((u>>16)&1u)) >> 16;
  return (unsigned short)r;
}
__device__ __forceinline__ float bf2f(unsigned short b){
  return __uint_as_float(((unsigned)b)<<16);
}
__device__ __forceinline__ short8 cvt8(const float* xv){
  union { short8 v; unsigned short u[8]; } H;
  #pragma unroll
  for (int j=0;j<8;j++) H.u[j] = f2bf(xv[j]);
  return H.v;
}
// RNE pack via HW instruction (same bits as f2bf for finite inputs)
__device__ __forceinline__ short8 cvt8pk(const float* x){
  union { short8 v; unsigned u32[4]; } H;
  #pragma unroll
  for (int i=0;i<4;i++)
    asm("v_cvt_pk_bf16_f32 %0, %1, %2" : "=v"(H.u32[i]) : "v"(x[2*i]), "v"(x[2*i+1]));
  return H.v;
}

__device__ __forceinline__ void gload_lds16(const void* gsrc, void* ldst){
  __builtin_amdgcn_global_load_lds(
    (const __attribute__((address_space(1))) void*)gsrc,
    (__attribute__((address_space(3))) void*)ldst, 16, 0, 0);
}

// bijective XCD swizzle (nwg % 8 == 0)
__device__ __forceinline__ int xcd_swz(int wg, int nwg){
  int cpx = nwg >> 3;
  return (wg & 7)*cpx + (wg >> 3);
}

// ---------------- merged prep + zbias ----------------
__global__ __launch_bounds__(256) void prep_zbias_kernel(
  const float* __restrict__ z, const float* __restrict__ lnz_gamma,
  const float* __restrict__ wz, unsigned short* __restrict__ bias3,
  const float* __restrict__ s, const float* __restrict__ adaln_gamma,
  unsigned short* __restrict__ s_ln_h, unsigned short* __restrict__ s_h,
  const float* __restrict__ a, float* __restrict__ a_n,
  const float* __restrict__ ws, const float* __restrict__ wskip,
  const float* __restrict__ wq, const float* __restrict__ wk,
  const float* __restrict__ wv, const float* __restrict__ wg,
  const float* __restrict__ wo, const float* __restrict__ wlast,
  unsigned short* __restrict__ Wt1, unsigned short* __restrict__ Wt2,
  unsigned short* __restrict__ Wt3, unsigned short* __restrict__ Wt4,
  const float* __restrict__ bq, const float* __restrict__ bg,
  float* __restrict__ biasq)
{
  union PZ {
    float tile[64][65];
    float zbuf[4][2][2048];
  };
  __shared__ PZ sm;
  int bid = blockIdx.x;
  int tid = threadIdx.x;

  if (bid < 1024){
    // ================= zbias =================
    int wave = tid>>6, lane = tid&63;
    int lr = lane&15, quad = lane>>4;

    short8 bwh[4];
    float w1 = 0.f;
    #pragma unroll
    for (int ks=0;ks<4;ks++){
      float wv_[8];
      #pragma unroll
      for (int j=0;j<8;j++){
        int k = ks*32 + quad*8 + j;
        wv_[j] = wz[k*NHEAD + lr]*lnz_gamma[k];
        w1 += wv_[j];
      }
      bwh[ks] = cvt8pk(wv_);
    }
    w1 += __shfl_xor(w1, 16);
    w1 += __shfl_xor(w1, 32);

    size_t group = (size_t)bid*4 + wave;
    const float* zg = z + group*(size_t)(NKW*CZ);
    unsigned short* outg = bias3 + group*2048;

    int rsub = lane>>5;
    int csw  = lane&31;
    auto stage = [&](int buf, int b){
      #pragma unroll
      for (int i=0;i<8;i++){
        int r  = 2*i + rsub;
        int gc = csw ^ (r & 7);
        gload_lds16(zg + (size_t)(b*16 + r)*CZ + gc*4, &sm.zbuf[wave][buf][i*256]);
      }
    };

    stage(0, 0);
    int buf = 0;
    #pragma unroll 1
    for (int b=0; b<8; ++b){
      if (b < 7){
        stage(buf^1, b+1);
        asm volatile("s_waitcnt vmcnt(8)" ::: "memory");
      } else {
        asm volatile("s_waitcnt vmcnt(0)" ::: "memory");
      }
      __builtin_amdgcn_sched_barrier(0);

      const float* rowp = &sm.zbuf[wave][buf][lr*128];
      int sswz = lr & 7;
      float4 p[8];
      #pragma unroll
      for (int ks=0;ks<4;ks++){
        int c0 = ks*8 + quad*2;
        p[ks*2]   = *(const float4*)(rowp + (size_t)((c0  )^sswz)*4);
        p[ks*2+1] = *(const float4*)(rowp + (size_t)((c0+1)^sswz)*4);
      }
      float sum=0.f, sq=0.f;
      #pragma unroll
      for (int t=0;t<8;t++){
        sum += p[t].x + p[t].y + p[t].z + p[t].w;
        sq  += p[t].x*p[t].x + p[t].y*p[t].y + p[t].z*p[t].z + p[t].w*p[t].w;
      }
      sum += __shfl_xor(sum,16); sum += __shfl_xor(sum,32);
      sq  += __shfl_xor(sq,16);  sq  += __shfl_xor(sq,32);
      float mean = sum*(1.f/CZ);
      float var  = sq*(1.f/CZ) - mean*mean;
      float rs = rsqrtf(var + 1e-5f);

      float4v c = (float4v){0.f,0.f,0.f,0.f};
      #pragma unroll
      for (int ks=0;ks<4;ks++){
        float xv[8];
        xv[0]=p[ks*2].x;   xv[1]=p[ks*2].y;   xv[2]=p[ks*2].z;   xv[3]=p[ks*2].w;
        xv[4]=p[ks*2+1].x; xv[5]=p[ks*2+1].y; xv[6]=p[ks*2+1].z; xv[7]=p[ks*2+1].w;
        c = __builtin_amdgcn_mfma_f32_16x16x32_bf16(cvt8pk(xv), bwh[ks], c, 0,0,0);
      }

      ushort4v o4;
      #pragma unroll
      for (int r=0;r<4;r++){
        int rrow = quad*4 + r;
        float m_r  = __shfl(mean, rrow);
        float rs_r = __shfl(rs, rrow);
        o4[r] = f2bf(rs_r*(c[r] - m_r*w1));
      }
      *(ushort4v*)(outg + lr*128 + b*16 + quad*4) = o4;
      buf ^= 1;
    }
    return;
  }
  bid -= 1024;

  if (bid < 1024){
    // ================= ln_s =================
    int wave = tid>>6, lane = tid&63;
    int row = bid*4 + wave;
    const float* x = s + (size_t)row*CS;
    float v[6]; float sum=0.f, sq=0.f;
    #pragma unroll
    for (int i=0;i<6;i++){ v[i]=x[lane+64*i]; sum+=v[i]; sq+=v[i]*v[i]; }
    #pragma unroll
    for (int off=32; off; off>>=1){ sum+=__shfl_xor(sum,off); sq+=__shfl_xor(sq,off); }
    float m = sum*(1.f/CS);
    float var = sq*(1.f/CS)-m*m;
    float rs = rsqrtf(var+1e-5f);
    #pragma unroll
    for (int i=0;i<6;i++){
      int c = lane+64*i;
      s_ln_h[(size_t)row*CS+c] = f2bf((v[i]-m)*rs*adaln_gamma[c]);
      s_h[(size_t)row*CS+c]    = f2bf(v[i]);
    }
    return;
  }
  bid -= 1024;

  if (bid < 1024){
    // ================= ln_a =================
    int wave = tid>>6, lane = tid&63;
    int row = bid*4 + wave;
    const float* x = a + (size_t)row*CA;
    float v[12]; float sum=0.f, sq=0.f;
    #pragma unroll
    for (int i=0;i<12;i++){ v[i]=x[lane+64*i]; sum+=v[i]; sq+=v[i]*v[i]; }
    #pragma unroll
    for (int off=32; off; off>>=1){ sum+=__shfl_xor(sum,off); sq+=__shfl_xor(sq,off); }
    float m = sum*(1.f/CA);
    float var = sq*(1.f/CA)-m*m;
    float rs = rsqrtf(var+1e-5f);
    float* o = a_n + (size_t)row*CA;
    #pragma unroll
    for (int i=0;i<12;i++) o[lane+64*i] = (v[i]-m)*rs;
    return;
  }
  bid -= 1024;

  if (bid < 936){
    // ================= weight transpose+cvt =================
    const float* src; unsigned short* dst; int K; int local;
    if      (bid < 72)  { src=ws;    dst=Wt1;                   K=CS; local=bid; }
    else if (bid < 144) { src=wskip; dst=Wt1 + (size_t)768*CS;  K=CS; local=bid-72; }
    else if (bid < 288) { src=wq;    dst=Wt2;                   K=CA; local=bid-144; }
    else if (bid < 432) { src=wk;    dst=Wt2 + (size_t)768*CA;  K=CA; local=bid-288; }
    else if (bid < 576) { src=wv;    dst=Wt2 + (size_t)1536*CA; K=CA; local=bid-432; }
    else if (bid < 720) { src=wg;    dst=Wt2 + (size_t)2304*CA; K=CA; local=bid-576; }
    else if (bid < 864) { src=wo;    dst=Wt3;                   K=CA; local=bid-720; }
    else                { src=wlast; dst=Wt4;                   K=CS; local=bid-864; }
    int ktiles = K/64;
    int kb = (local % ktiles)*64, nb = (local / ktiles)*64;
    int c = tid & 63, r0 = tid >> 6;
    #pragma unroll
    for (int i=0;i<16;i++){
      int r = r0 + 4*i;
      sm.tile[r][c] = src[(size_t)(kb+r)*CA + nb + c];
    }
    __syncthreads();
    #pragma unroll
    for (int i=0;i<16;i++){
      int r = r0 + 4*i;          // n-local
      dst[(size_t)(nb+r)*K + kb + c] = f2bf(sm.tile[c][r]);
    }
    return;
  }
  bid -= 936;

  // ================= biasq =================
  int i = bid*256 + tid;
  float v = 0.f;
  if (i < 768) v = bq[i];
  else if (i >= 2304) v = bg[i-2304];
  biasq[i] = v;
}

// ---------------- fused adaln GEMM, 2-phase dbuf (T3-minimum) ----------------
// a_ln = sigmoid(s_ln@ws + bs)*a_n + s_ln@wskip -> bf16
__global__ __launch_bounds__(256) void adaln_gemm(
  const unsigned short* __restrict__ A, const unsigned short* __restrict__ Bt,
  const float* __restrict__ bs, const float* __restrict__ a_n,
  unsigned short* __restrict__ outh)
{
  __shared__ unsigned short Ash[2][128*32];
  __shared__ unsigned short B1sh[2][128*32];
  __shared__ unsigned short B2sh[2][128*32];

  int tid = threadIdx.x;
  int w = tid >> 6, lane = tid & 63;
  int lr = lane & 15, quad = lane >> 4;
  int wg = xcd_swz(blockIdx.y*gridDim.x + blockIdx.x, gridDim.x*gridDim.y);
  int bx = wg % gridDim.x, by = wg / gridDim.x;
  int m0 = by*128, n0 = bx*128;
  int mbase = (w&1)*64, nbase = (w>>1)*64;

  float4v acc1[4][4], acc2[4][4];
  #pragma unroll
  for (int i=0;i<4;i++)
    #pragma unroll
    for (int j=0;j<4;j++){
      acc1[i][j] = (float4v){0.f,0.f,0.f,0.f};
      acc2[i][j] = (float4v){0.f,0.f,0.f,0.f};
    }

  int grow = w*32 + (lane>>2);
  int gcol8 = (lane&3)*8;

  auto stage = [&](int buf, int k0){
    #pragma unroll
    for (int i=0;i<2;i++){
      int rA = grow + i*16;
      gload_lds16(A  + (size_t)(m0 + rA)*CS + k0 + gcol8, &Ash[buf][(w*32 + i*16)*32]);
      gload_lds16(Bt + (size_t)(n0 + rA)*CS + k0 + gcol8, &B1sh[buf][(w*32 + i*16)*32]);
      gload_lds16(Bt + (size_t)(768 + n0 + rA)*CS + k0 + gcol8, &B2sh[buf][(w*32 + i*16)*32]);
    }
  };

  const int NT = CS/32;   // 12
  stage(0, 0);
  __syncthreads();        // drains vmcnt(0) implicitly
  int cur = 0;
  #pragma unroll 1
  for (int t=0; t<NT; ++t){
    if (t+1 < NT) stage(cur^1, (t+1)*32);   // issue next-tile loads; latency hides under MFMA
    short8 af[4], b1f[4], b2f[4];
    #pragma unroll
    for (int mi=0;mi<4;mi++)
      af[mi] = *(const short8*)&Ash[cur][(mbase + mi*16 + lr)*32 + quad*8];
    #pragma unroll
    for (int ni=0;ni<4;ni++){
      b1f[ni] = *(const short8*)&B1sh[cur][(nbase + ni*16 + lr)*32 + quad*8];
      b2f[ni] = *(const short8*)&B2sh[cur][(nbase + ni*16 + lr)*32 + quad*8];
    }
    #pragma unroll
    for (int mi=0;mi<4;mi++)
      #pragma unroll
      for (int ni=0;ni<4;ni++){
        acc1[mi][ni] = __builtin_amdgcn_mfma_f32_16x16x32_bf16(af[mi], b1f[ni], acc1[mi][ni], 0,0,0);
        acc2[mi][ni] = __builtin_amdgcn_mfma_f32_16x16x32_bf16(af[mi], b2f[ni], acc2[mi][ni], 0,0,0);
      }
    if (t+1 < NT){ __syncthreads(); cur ^= 1; }
  }

  #pragma unroll
  for (int ni=0;ni<4;ni++){
    int col = n0 + nbase + ni*16 + lr;
    float bsv = bs[col];
    #pragma unroll
    for (int mi=0;mi<4;mi++){
      #pragma unroll
      for (int reg=0;reg<4;reg++){
        int row = m0 + mbase + mi*16 + quad*4 + reg;
        float v = sigmoidf_(acc1[mi][ni][reg] + bsv)*a_n[(size_t)row*CA + col] + acc2[mi][ni][reg];
        outh[(size_t)row*CA + col] = f2bf(v);
      }
    }
  }
}

// ---------------- bf16 MFMA GEMM, 2-phase dbuf + XCD swizzle ----------------
// MODE 1: bf16 out = f2bf(acc1 + bias1)
// MODE 3: f32 out = sigmoid(acc2 + bias2) * (acc1 + bias1)  (tiles NT1..NT1+NT2 feed acc2)
template<int MODE>
__global__ __launch_bounds__(256) void gemm_bf16(
  const unsigned short* __restrict__ A1, const unsigned short* __restrict__ B1,
  const float* __restrict__ bias1, int K1,
  const unsigned short* __restrict__ A2, const unsigned short* __restrict__ B2,
  const float* __restrict__ bias2, int K2,
  void* __restrict__ outp, int M, int N)
{
  __shared__ unsigned short Ash[2][128*32];
  __shared__ unsigned short Bsh[2][128*32];

  int tid = threadIdx.x;
  int w = tid >> 6, lane = tid & 63;
  int lr = lane & 15, quad = lane >> 4;
  int wg = xcd_swz(blockIdx.y*gridDim.x + blockIdx.x, gridDim.x*gridDim.y);
  int bx = wg % gridDim.x, by = wg / gridDim.x;
  int m0 = by*128, n0 = bx*128;
  int mbase = (w&1)*64, nbase = (w>>1)*64;

  float4v acc1[4][4];
  float4v acc2[4][4];
  #pragma unroll
  for (int i=0;i<4;i++)
    #pragma unroll
    for (int j=0;j<4;j++){
      acc1[i][j] = (float4v){0.f,0.f,0.f,0.f};
      if constexpr (MODE == 3) acc2[i][j] = (float4v){0.f,0.f,0.f,0.f};
    }

  int grow = w*32 + (lane>>2);
  int gcol8 = (lane&3)*8;

  const int NT1 = K1/32;
  const int NT2 = (MODE==3) ? K2/32 : 0;
  const int NT  = NT1 + NT2;

  auto stage = [&](int buf, int t){
    const unsigned short* Ap; const unsigned short* Bp; int K, k0;
    if (t < NT1){ Ap=A1; Bp=B1; K=K1; k0=t*32; }
    else        { Ap=A2; Bp=B2; K=K2; k0=(t-NT1)*32; }
    #pragma unroll
    for (int i=0;i<2;i++){
      int rA = grow + i*16;
      gload_lds16(Ap + (size_t)(m0 + rA)*K + k0 + gcol8, &Ash[buf][(w*32 + i*16)*32]);
      gload_lds16(Bp + (size_t)(n0 + rA)*K + k0 + gcol8, &Bsh[buf][(w*32 + i*16)*32]);
    }
  };

  stage(0, 0);
  __syncthreads();
  int cur = 0;
  #pragma unroll 1
  for (int t=0; t<NT; ++t){
    if (t+1 < NT) stage(cur^1, t+1);
    short8 af[4], bf[4];
    #pragma unroll
    for (int mi=0;mi<4;mi++)
      af[mi] = *(const short8*)&Ash[cur][(mbase + mi*16 + lr)*32 + quad*8];
    #pragma unroll
    for (int ni=0;ni<4;ni++)
      bf[ni] = *(const short8*)&Bsh[cur][(nbase + ni*16 + lr)*32 + quad*8];
    if (MODE != 3 || t < NT1){
      #pragma unroll
      for (int mi=0;mi<4;mi++)
        #pragma unroll
        for (int ni=0;ni<4;ni++)
          acc1[mi][ni] = __builtin_amdgcn_mfma_f32_16x16x32_bf16(af[mi], bf[ni], acc1[mi][ni], 0,0,0);
    } else {
      #pragma unroll
      for (int mi=0;mi<4;mi++)
        #pragma unroll
        for (int ni=0;ni<4;ni++)
          acc2[mi][ni] = __builtin_amdgcn_mfma_f32_16x16x32_bf16(af[mi], bf[ni], acc2[mi][ni], 0,0,0);
    }
    if (t+1 < NT){ __syncthreads(); cur ^= 1; }
  }

  #pragma unroll
  for (int ni=0;ni<4;ni++){
    int col = n0 + nbase + ni*16 + lr;
    float bv1 = bias1 ? bias1[col] : 0.f;
    float bv2 = (MODE==3 && bias2) ? bias2[col] : 0.f;
    #pragma unroll
    for (int mi=0;mi<4;mi++){
      #pragma unroll
      for (int reg=0;reg<4;reg++){
        int row = m0 + mbase + mi*16 + quad*4 + reg;
        float x1 = acc1[mi][ni][reg] + bv1;
        if constexpr (MODE == 1)
          ((unsigned short*)outp)[(size_t)row*N + col] = f2bf(x1);
        else
          ((float*)outp)[(size_t)row*N + col] = sigmoidf_(acc2[mi][ni][reg] + bv2)*x1;
      }
    }
  }
}

// ---------------- attention: one wave per (w,h); V staged in LDS ----------------
__global__ __launch_bounds__(256) void attn_kernel(
  const unsigned short* __restrict__ qh,
  const unsigned short* __restrict__ bias3h,
  unsigned short* __restrict__ og)
{
  __shared__ unsigned short Vs[128*192];   // block's 4 heads V window, chunk-swizzled
  __shared__ unsigned short Pb[4][32*40];
  int tid = threadIdx.x, wave = tid>>6, lane = tid&63;
  int lr = lane&15, quad = lane>>4;
  int w = blockIdx.x, h = blockIdx.y*4 + wave;
  int start = w*NQW - 48;
  const float scale = 0.14433756729740643f;  // 1/sqrt(48)

  // ---- cooperative V staging (coalesced rows, XOR chunk swizzle) ----
  {
    int hbase = blockIdx.y*4*DH;
    #pragma unroll
    for (int it=0; it<12; ++it){
      int c = it*256 + tid;                 // 0..3071 chunk id
      int key = c/24, cc = c - key*24;      // cc: 8-ushort chunk index 0..23
      int kr = min(max(start+key,0),N_TOK-1);
      short8 v = *(const short8*)&qh[(size_t)kr*3072 + 1536 + hbase + cc*8];
      int cs = cc ^ (((key>>3)&3)*2);
      *(short8*)&Vs[key*192 + cs*8] = v;
    }
  }

  short8 zero8 = {0,0,0,0,0,0,0,0};

  // ---- Q A-frags ----
  short8 aq[2][2];
  #pragma unroll
  for (int mt=0;mt<2;mt++){
    int row = w*NQW + mt*16 + lr;
    const unsigned short* qp = qh + (size_t)row*3072 + h*DH;
    aq[mt][0] = *(const short8*)(qp + quad*8);
    aq[mt][1] = (quad<2) ? *(const short8*)(qp + 32 + quad*8) : zero8;
  }

  // ---- QK^T ----
  float4v c[2][8];
  #pragma unroll
  for (int mt=0;mt<2;mt++)
    #pragma unroll
    for (int nt=0;nt<8;nt++) c[mt][nt] = (float4v){0.f,0.f,0.f,0.f};

  #pragma unroll 2
  for (int nt=0;nt<8;nt++){
    int krc = min(max(start + nt*16 + lr,0),N_TOK-1);
    const unsigned short* kp = qh + (size_t)krc*3072 + 768 + h*DH;
    short8 bk0 = *(const short8*)(kp + quad*8);
    short8 bk1 = (quad<2) ? *(const short8*)(kp + 32 + quad*8) : zero8;
    #pragma unroll
    for (int mt=0;mt<2;mt++){
      c[mt][nt] = __builtin_amdgcn_mfma_f32_16x16x32_bf16(aq[mt][0], bk0, c[mt][nt], 0,0,0);
      c[mt][nt] = __builtin_amdgcn_mfma_f32_16x16x32_bf16(aq[mt][1], bk1, c[mt][nt], 0,0,0);
    }
  }

  // ---- bias + mask + softmax in registers ----
  float rmax[2][4], rsum[2][4];
  #pragma unroll
  for (int mt=0;mt<2;mt++)
    #pragma unroll
    for (int r=0;r<4;r++){ rmax[mt][r] = -3.0e38f; rsum[mt][r] = 0.f; }

  #pragma unroll
  for (int nt=0;nt<8;nt++){
    int key = start + nt*16 + lr;
    bool valid = (key>=0) && (key<N_TOK);
    #pragma unroll
    for (int mt=0;mt<2;mt++){
      #pragma unroll
      for (int r=0;r<4;r++){
        int q = mt*16 + quad*4 + r;
        float bv = bf2f(bias3h[(((size_t)(w*NQW+q))*NHEAD + h)*128 + nt*16 + lr]);
        float v = valid ? (c[mt][nt][r]*scale + bv) : -1e9f;
        c[mt][nt][r] = v;
        rmax[mt][r] = fmaxf(rmax[mt][r], v);
      }
    }
  }
  #pragma unroll
  for (int mt=0;mt<2;mt++)
    #pragma unroll
    for (int r=0;r<4;r++){
      float m = rmax[mt][r];
      m = fmaxf(m, __shfl_xor(m,1)); m = fmaxf(m, __shfl_xor(m,2));
      m = fmaxf(m, __shfl_xor(m,4)); m = fmaxf(m, __shfl_xor(m,8));
      rmax[mt][r] = m;
    }
  #pragma unroll
  for (int nt=0;nt<8;nt++)
    #pragma unroll
    for (int mt=0;mt<2;mt++)
      #pragma unroll
      for (int r=0;r<4;r++){
        float e = __expf(c[mt][nt][r] - rmax[mt][r]);
        c[mt][nt][r] = e;
        rsum[mt][r] += e;
      }
  #pragma unroll
  for (int mt=0;mt<2;mt++)
    #pragma unroll
    for (int r=0;r<4;r++){
      float sv = rsum[mt][r];
      sv += __shfl_xor(sv,1); sv += __shfl_xor(sv,2);
      sv += __shfl_xor(sv,4); sv += __shfl_xor(sv,8);
      rsum[mt][r] = 1.f/sv;
    }

  __syncthreads();   // Vs staged by all waves

  // ---- PV: P through per-wave LDS, V from swizzled LDS ----
  unsigned short* ph = &Pb[wave][0];
  float4v o[2][3];
  #pragma unroll
  for (int mt=0;mt<2;mt++)
    #pragma unroll
    for (int no=0;no<3;no++) o[mt][no] = (float4v){0.f,0.f,0.f,0.f};

  #pragma unroll 1
  for (int c2=0;c2<2;c2++){
    #pragma unroll 1
    for (int ks=0;ks<2;ks++){
      int ntb = c2*4 + ks*2;
      #pragma unroll
      for (int t=0;t<2;t++){
        int nt = ntb + t;
        #pragma unroll
        for (int mt=0;mt<2;mt++){
          #pragma unroll
          for (int r=0;r<4;r++){
            int q = mt*16 + quad*4 + r;
            ph[q*40 + t*16 + lr] = f2bf(c[mt][nt][r]*rsum[mt][r]);
          }
        }
      }
      short8 pa[2];
      #pragma unroll
      for (int mt=0;mt<2;mt++)
        pa[mt] = *(const short8*)&ph[(mt*16+lr)*40 + quad*8];
      #pragma unroll
      for (int no=0;no<3;no++){
        union { short8 v; unsigned short u[8]; } V;
        int col = wave*DH + no*16 + lr;
        int chunk = col >> 3;
        int cs = (chunk ^ (quad*2))*8 + (col & 7);
        #pragma unroll
        for (int j=0;j<8;j++){
          int key = c2*64 + ks*32 + quad*8 + j;
          V.u[j] = Vs[key*192 + cs];
        }
        #pragma unroll
        for (int mt=0;mt<2;mt++)
          o[mt][no] = __builtin_amdgcn_mfma_f32_16x16x32_bf16(pa[mt], V.v, o[mt][no], 0,0,0);
      }
    }
  }

  // ---- epilogue: gate + store bf16 ----
  #pragma unroll
  for (int mt=0;mt<2;mt++){
    #pragma unroll
    for (int no=0;no<3;no++){
      int d = no*16 + lr;
      #pragma unroll
      for (int r=0;r<4;r++){
        int q = mt*16 + quad*4 + r;
        size_t grow = (size_t)(w*NQW + q);
        float g = bf2f(qh[grow*3072 + 2304 + h*DH + d]);
        og[grow*CA + h*DH + d] = f2bf(o[mt][no][r] * sigmoidf_(g));
      }
    }
  }
}

extern "C" void kernel_launch(void* const* d_in, const int* in_sizes, int n_in,
                              void* d_out, int out_size, void* d_ws, size_t ws_size,
                              hipStream_t stream)
{
  const float* a            = (const float*)d_in[0];
  const float* s            = (const float*)d_in[1];
  const float* z            = (const float*)d_in[2];
  const float* adaln_gamma  = (const float*)d_in[3];
  const float* adaln_ws     = (const float*)d_in[4];
  const float* adaln_bs     = (const float*)d_in[5];
  const float* adaln_wskip  = (const float*)d_in[6];
  const float* lnz_gamma    = (const float*)d_in[7];
  const float* wz           = (const float*)d_in[8];
  const float* wq           = (const float*)d_in[9];
  const float* bq           = (const float*)d_in[10];
  const float* wk           = (const float*)d_in[11];
  const float* wv           = (const float*)d_in[12];
  const float* wg           = (const float*)d_in[13];
  const float* bg           = (const float*)d_in[14];
  const float* wo           = (const float*)d_in[15];
  const float* bo           = (const float*)d_in[16];
  const float* w_last       = (const float*)d_in[17];
  const float* b_last       = (const float*)d_in[18];
  float* out = (float*)d_out;

  char* base = (char*)d_ws;
  size_t off = 0;
  auto alloc = [&](size_t bytes)->char*{ char* p = base + off; off += (bytes + 255) & ~(size_t)255; return p; };

  unsigned short* s_ln_h = (unsigned short*)alloc((size_t)N_TOK*CS*2);
  unsigned short* s_h    = (unsigned short*)alloc((size_t)N_TOK*CS*2);
  float*          a_n    = (float*)alloc((size_t)N_TOK*CA*4);
  unsigned short* a_ln_h = (unsigned short*)alloc((size_t)N_TOK*CA*2);
  unsigned short* og_h   = (unsigned short*)alloc((size_t)N_TOK*CA*2);
  unsigned short* Wt1    = (unsigned short*)alloc((size_t)1536*CS*2);
  unsigned short* Wt2    = (unsigned short*)alloc((size_t)3072*CA*2);
  unsigned short* Wt3    = (unsigned short*)alloc((size_t)CA*CA*2);
  unsigned short* Wt4    = (unsigned short*)alloc((size_t)CA*CS*2);
  unsigned short* bias3h = (unsigned short*)alloc((size_t)N_TOK*NHEAD*NKW*2);
  unsigned short* qkvg_h = (unsigned short*)alloc((size_t)N_TOK*3072*2);
  float*          biasq  = (float*)alloc((size_t)3072*4);

  prep_zbias_kernel<<<dim3(1024+1024+1024+936+12), 256, 0, stream>>>(
      z, lnz_gamma, wz, bias3h,
      s, adaln_gamma, s_ln_h, s_h, a, a_n,
      adaln_ws, adaln_wskip, wq, wk, wv, wg, wo, w_last,
      Wt1, Wt2, Wt3, Wt4, bq, bg, biasq);

  adaln_gemm<<<dim3(CA/128, N_TOK/128), 256, 0, stream>>>(s_ln_h, Wt1, adaln_bs, a_n, a_ln_h);

  gemm_bf16<1><<<dim3(3072/128, N_TOK/128), 256, 0, stream>>>(
      a_ln_h, Wt2, biasq, CA, nullptr, nullptr, nullptr, 0, qkvg_h, N_TOK, 3072);

  attn_kernel<<<dim3(NBLK, 4), 256, 0, stream>>>(qkvg_h, bias3h, og_h);

  gemm_bf16<3><<<dim3(CA/128, N_TOK/128), 256, 0, stream>>>(
      og_h, Wt3, bo, CA, s_h, Wt4, b_last, CS, out, N_TOK, CA);
}

// Round 11
// 220.994 us; speedup vs baseline: 1.1436x; 1.1436x over previous
//
#include <hip/hip_runtime.h>
#include <hip/hip_bf16.h>
#include <math.h>

#define N_TOK 4096
#define CA 768
#define CS 384
#define CZ 128
#define NHEAD 16
#define DH 48
#define NQW 32
#define NKW 128
#define NBLK 128

typedef __attribute__((ext_vector_type(8))) short short8;
typedef __attribute__((ext_vector_type(4))) float float4v;
typedef __attribute__((ext_vector_type(4))) unsigned short ushort4v;

__device__ __forceinline__ float sigmoidf_(float x){ return 1.0f/(1.0f+__expf(-x)); }

__device__ __forceinline__ unsigned short f2bf(float x){
  unsigned u = __float_as_uint(x);
  unsigned r = (u + 0x7FFFu + ((u>>16)&1u)) >> 16;
  return (unsigned short)r;
}
__device__ __forceinline__ float bf2f(unsigned short b){
  return __uint_as_float(((unsigned)b)<<16);
}
__device__ __forceinline__ short8 cvt8(const float* xv){
  union { short8 v; unsigned short u[8]; } H;
  #pragma unroll
  for (int j=0;j<8;j++) H.u[j] = f2bf(xv[j]);
  return H.v;
}
// RNE pack via HW instruction (same bits as f2bf for finite inputs)
__device__ __forceinline__ short8 cvt8pk(const float* x){
  union { short8 v; unsigned u32[4]; } H;
  #pragma unroll
  for (int i=0;i<4;i++)
    asm("v_cvt_pk_bf16_f32 %0, %1, %2" : "=v"(H.u32[i]) : "v"(x[2*i]), "v"(x[2*i+1]));
  return H.v;
}

__device__ __forceinline__ void gload_lds16(const void* gsrc, void* ldst){
  __builtin_amdgcn_global_load_lds(
    (const __attribute__((address_space(1))) void*)gsrc,
    (__attribute__((address_space(3))) void*)ldst, 16, 0, 0);
}

// bijective XCD swizzle (nwg % 8 == 0)
__device__ __forceinline__ int xcd_swz(int wg, int nwg){
  int cpx = nwg >> 3;
  return (wg & 7)*cpx + (wg >> 3);
}

// ---------------- merged prep + zbias (32KB LDS union -> 5 blocks/CU) ----------------
// [0,2048): zbias (2 groups each, waves 0-1) ; +1024 ln_s ; +1024 ln_a ; +936 cvtT ; +12 biasq
__global__ __launch_bounds__(256) void prep_zbias_kernel(
  const float* __restrict__ z, const float* __restrict__ lnz_gamma,
  const float* __restrict__ wz, unsigned short* __restrict__ bias3,
  const float* __restrict__ s, const float* __restrict__ adaln_gamma,
  unsigned short* __restrict__ s_ln_h, unsigned short* __restrict__ s_h,
  const float* __restrict__ a, float* __restrict__ a_n,
  const float* __restrict__ ws, const float* __restrict__ wskip,
  const float* __restrict__ wq, const float* __restrict__ wk,
  const float* __restrict__ wv, const float* __restrict__ wg,
  const float* __restrict__ wo, const float* __restrict__ wlast,
  unsigned short* __restrict__ Wt1, unsigned short* __restrict__ Wt2,
  unsigned short* __restrict__ Wt3, unsigned short* __restrict__ Wt4,
  const float* __restrict__ bq, const float* __restrict__ bg,
  float* __restrict__ biasq)
{
  union PZ {
    float tile[64][65];       // 16.6 KB
    float zbuf[2][2][2048];   // 32 KB (2 zbias waves, dbuf)
  };
  __shared__ PZ sm;
  int bid = blockIdx.x;
  int tid = threadIdx.x;

  if (bid < 2048){
    // ================= zbias (waves 0,1 only) =================
    int wave = tid>>6, lane = tid&63;
    if (wave >= 2) return;
    int lr = lane&15, quad = lane>>4;

    short8 bwh[4];
    float w1 = 0.f;
    #pragma unroll
    for (int ks=0;ks<4;ks++){
      float wv_[8];
      #pragma unroll
      for (int j=0;j<8;j++){
        int k = ks*32 + quad*8 + j;
        wv_[j] = wz[k*NHEAD + lr]*lnz_gamma[k];
        w1 += wv_[j];
      }
      bwh[ks] = cvt8pk(wv_);
    }
    w1 += __shfl_xor(w1, 16);
    w1 += __shfl_xor(w1, 32);

    size_t group = (size_t)bid*2 + wave;   // 0..4095
    const float* zg = z + group*(size_t)(NKW*CZ);
    unsigned short* outg = bias3 + group*2048;

    int rsub = lane>>5;
    int csw  = lane&31;
    auto stage = [&](int buf, int b){
      #pragma unroll
      for (int i=0;i<8;i++){
        int r  = 2*i + rsub;
        int gc = csw ^ (r & 7);
        gload_lds16(zg + (size_t)(b*16 + r)*CZ + gc*4, &sm.zbuf[wave][buf][i*256]);
      }
    };

    stage(0, 0);
    int buf = 0;
    #pragma unroll 1
    for (int b=0; b<8; ++b){
      if (b < 7){
        stage(buf^1, b+1);
        asm volatile("s_waitcnt vmcnt(8)" ::: "memory");
      } else {
        asm volatile("s_waitcnt vmcnt(0)" ::: "memory");
      }
      __builtin_amdgcn_sched_barrier(0);

      const float* rowp = &sm.zbuf[wave][buf][lr*128];
      int sswz = lr & 7;
      float4 p[8];
      #pragma unroll
      for (int ks=0;ks<4;ks++){
        int c0 = ks*8 + quad*2;
        p[ks*2]   = *(const float4*)(rowp + (size_t)((c0  )^sswz)*4);
        p[ks*2+1] = *(const float4*)(rowp + (size_t)((c0+1)^sswz)*4);
      }
      float sum=0.f, sq=0.f;
      #pragma unroll
      for (int t=0;t<8;t++){
        sum += p[t].x + p[t].y + p[t].z + p[t].w;
        sq  += p[t].x*p[t].x + p[t].y*p[t].y + p[t].z*p[t].z + p[t].w*p[t].w;
      }
      sum += __shfl_xor(sum,16); sum += __shfl_xor(sum,32);
      sq  += __shfl_xor(sq,16);  sq  += __shfl_xor(sq,32);
      float mean = sum*(1.f/CZ);
      float var  = sq*(1.f/CZ) - mean*mean;
      float rs = rsqrtf(var + 1e-5f);

      float4v c = (float4v){0.f,0.f,0.f,0.f};
      #pragma unroll
      for (int ks=0;ks<4;ks++){
        float xv[8];
        xv[0]=p[ks*2].x;   xv[1]=p[ks*2].y;   xv[2]=p[ks*2].z;   xv[3]=p[ks*2].w;
        xv[4]=p[ks*2+1].x; xv[5]=p[ks*2+1].y; xv[6]=p[ks*2+1].z; xv[7]=p[ks*2+1].w;
        c = __builtin_amdgcn_mfma_f32_16x16x32_bf16(cvt8pk(xv), bwh[ks], c, 0,0,0);
      }

      ushort4v o4;
      #pragma unroll
      for (int r=0;r<4;r++){
        int rrow = quad*4 + r;
        float m_r  = __shfl(mean, rrow);
        float rs_r = __shfl(rs, rrow);
        o4[r] = f2bf(rs_r*(c[r] - m_r*w1));
      }
      *(ushort4v*)(outg + lr*128 + b*16 + quad*4) = o4;
      buf ^= 1;
    }
    return;
  }
  bid -= 2048;

  if (bid < 1024){
    // ================= ln_s =================
    int wave = tid>>6, lane = tid&63;
    int row = bid*4 + wave;
    const float* x = s + (size_t)row*CS;
    float v[6]; float sum=0.f, sq=0.f;
    #pragma unroll
    for (int i=0;i<6;i++){ v[i]=x[lane+64*i]; sum+=v[i]; sq+=v[i]*v[i]; }
    #pragma unroll
    for (int off=32; off; off>>=1){ sum+=__shfl_xor(sum,off); sq+=__shfl_xor(sq,off); }
    float m = sum*(1.f/CS);
    float var = sq*(1.f/CS)-m*m;
    float rs = rsqrtf(var+1e-5f);
    #pragma unroll
    for (int i=0;i<6;i++){
      int c = lane+64*i;
      s_ln_h[(size_t)row*CS+c] = f2bf((v[i]-m)*rs*adaln_gamma[c]);
      s_h[(size_t)row*CS+c]    = f2bf(v[i]);
    }
    return;
  }
  bid -= 1024;

  if (bid < 1024){
    // ================= ln_a =================
    int wave = tid>>6, lane = tid&63;
    int row = bid*4 + wave;
    const float* x = a + (size_t)row*CA;
    float v[12]; float sum=0.f, sq=0.f;
    #pragma unroll
    for (int i=0;i<12;i++){ v[i]=x[lane+64*i]; sum+=v[i]; sq+=v[i]*v[i]; }
    #pragma unroll
    for (int off=32; off; off>>=1){ sum+=__shfl_xor(sum,off); sq+=__shfl_xor(sq,off); }
    float m = sum*(1.f/CA);
    float var = sq*(1.f/CA)-m*m;
    float rs = rsqrtf(var+1e-5f);
    float* o = a_n + (size_t)row*CA;
    #pragma unroll
    for (int i=0;i<12;i++) o[lane+64*i] = (v[i]-m)*rs;
    return;
  }
  bid -= 1024;

  if (bid < 936){
    // ================= weight transpose+cvt =================
    const float* src; unsigned short* dst; int K; int local;
    if      (bid < 72)  { src=ws;    dst=Wt1;                   K=CS; local=bid; }
    else if (bid < 144) { src=wskip; dst=Wt1 + (size_t)768*CS;  K=CS; local=bid-72; }
    else if (bid < 288) { src=wq;    dst=Wt2;                   K=CA; local=bid-144; }
    else if (bid < 432) { src=wk;    dst=Wt2 + (size_t)768*CA;  K=CA; local=bid-288; }
    else if (bid < 576) { src=wv;    dst=Wt2 + (size_t)1536*CA; K=CA; local=bid-432; }
    else if (bid < 720) { src=wg;    dst=Wt2 + (size_t)2304*CA; K=CA; local=bid-576; }
    else if (bid < 864) { src=wo;    dst=Wt3;                   K=CA; local=bid-720; }
    else                { src=wlast; dst=Wt4;                   K=CS; local=bid-864; }
    int ktiles = K/64;
    int kb = (local % ktiles)*64, nb = (local / ktiles)*64;
    int c = tid & 63, r0 = tid >> 6;
    #pragma unroll
    for (int i=0;i<16;i++){
      int r = r0 + 4*i;
      sm.tile[r][c] = src[(size_t)(kb+r)*CA + nb + c];
    }
    __syncthreads();
    #pragma unroll
    for (int i=0;i<16;i++){
      int r = r0 + 4*i;          // n-local
      dst[(size_t)(nb+r)*K + kb + c] = f2bf(sm.tile[c][r]);
    }
    return;
  }
  bid -= 936;

  // ================= biasq =================
  int i = bid*256 + tid;
  float v = 0.f;
  if (i < 768) v = bq[i];
  else if (i >= 2304) v = bg[i-2304];
  biasq[i] = v;
}

// ---------------- adaln GEMM, 64x128 tile (grid 6 x 64 = 384 blocks) ----------------
// a_ln = sigmoid(s_ln@ws + bs)*a_n + s_ln@wskip -> bf16
__global__ __launch_bounds__(256) void adaln_gemm(
  const unsigned short* __restrict__ A, const unsigned short* __restrict__ Bt,
  const float* __restrict__ bs, const float* __restrict__ a_n,
  unsigned short* __restrict__ outh)
{
  __shared__ unsigned short Ash[64*32];
  __shared__ unsigned short B1sh[128*32];
  __shared__ unsigned short B2sh[128*32];

  int tid = threadIdx.x;
  int w = tid >> 6, lane = tid & 63;
  int lr = lane & 15, quad = lane >> 4;
  // grid: x = CA/128 = 6, y = 4096/64 = 64 -> 384 blocks
  int wg = xcd_swz(blockIdx.y*gridDim.x + blockIdx.x, gridDim.x*gridDim.y);
  int bx = wg % gridDim.x, by = wg / gridDim.x;
  int m0 = by*64, n0 = bx*128;
  int mbase = (w&1)*32, nbase = (w>>1)*64;

  float4v acc1[2][4], acc2[2][4];
  #pragma unroll
  for (int i=0;i<2;i++)
    #pragma unroll
    for (int j=0;j<4;j++){
      acc1[i][j] = (float4v){0.f,0.f,0.f,0.f};
      acc2[i][j] = (float4v){0.f,0.f,0.f,0.f};
    }

  int growB = w*32 + (lane>>2);   // B rows 0..127
  int growA = w*16 + (lane>>2);   // A rows 0..63
  int gcol8 = (lane&3)*8;

  for (int k0=0; k0<CS; k0+=32){
    __syncthreads();
    gload_lds16(A + (size_t)(m0 + growA)*CS + k0 + gcol8, &Ash[(w*16)*32]);
    #pragma unroll
    for (int i=0;i<2;i++){
      int rB = growB + i*16;
      gload_lds16(Bt + (size_t)(n0 + rB)*CS + k0 + gcol8, &B1sh[(w*32 + i*16)*32]);
      gload_lds16(Bt + (size_t)(768 + n0 + rB)*CS + k0 + gcol8, &B2sh[(w*32 + i*16)*32]);
    }
    __syncthreads();

    short8 af[2], b1f[4], b2f[4];
    #pragma unroll
    for (int mi=0;mi<2;mi++)
      af[mi] = *(const short8*)&Ash[(mbase + mi*16 + lr)*32 + quad*8];
    #pragma unroll
    for (int ni=0;ni<4;ni++){
      b1f[ni] = *(const short8*)&B1sh[(nbase + ni*16 + lr)*32 + quad*8];
      b2f[ni] = *(const short8*)&B2sh[(nbase + ni*16 + lr)*32 + quad*8];
    }
    #pragma unroll
    for (int mi=0;mi<2;mi++)
      #pragma unroll
      for (int ni=0;ni<4;ni++){
        acc1[mi][ni] = __builtin_amdgcn_mfma_f32_16x16x32_bf16(af[mi], b1f[ni], acc1[mi][ni], 0,0,0);
        acc2[mi][ni] = __builtin_amdgcn_mfma_f32_16x16x32_bf16(af[mi], b2f[ni], acc2[mi][ni], 0,0,0);
      }
  }

  #pragma unroll
  for (int ni=0;ni<4;ni++){
    int col = n0 + nbase + ni*16 + lr;
    float bsv = bs[col];
    #pragma unroll
    for (int mi=0;mi<2;mi++){
      #pragma unroll
      for (int reg=0;reg<4;reg++){
        int row = m0 + mbase + mi*16 + quad*4 + reg;
        float v = sigmoidf_(acc1[mi][ni][reg] + bsv)*a_n[(size_t)row*CA + col] + acc2[mi][ni][reg];
        outh[(size_t)row*CA + col] = f2bf(v);
      }
    }
  }
}

// ---------------- final dual-K GEMM, 64x128 tile (grid 6 x 64 = 384 blocks) ----------------
// out = sigmoid(s@wlast+blast) * (og@wo+bo)  (f32 out)
__global__ __launch_bounds__(256) void final_gemm(
  const unsigned short* __restrict__ A1, const unsigned short* __restrict__ B1,
  const float* __restrict__ bias1,
  const unsigned short* __restrict__ A2, const unsigned short* __restrict__ B2,
  const float* __restrict__ bias2,
  float* __restrict__ outp)
{
  __shared__ unsigned short Ash[64*32];
  __shared__ unsigned short Bsh[128*32];

  int tid = threadIdx.x;
  int w = tid >> 6, lane = tid & 63;
  int lr = lane & 15, quad = lane >> 4;
  int wg = xcd_swz(blockIdx.y*gridDim.x + blockIdx.x, gridDim.x*gridDim.y);
  int bx = wg % gridDim.x, by = wg / gridDim.x;
  int m0 = by*64, n0 = bx*128;
  int mbase = (w&1)*32, nbase = (w>>1)*64;

  float4v acc1[2][4], acc2[2][4];
  #pragma unroll
  for (int i=0;i<2;i++)
    #pragma unroll
    for (int j=0;j<4;j++){
      acc1[i][j] = (float4v){0.f,0.f,0.f,0.f};
      acc2[i][j] = (float4v){0.f,0.f,0.f,0.f};
    }

  int growB = w*32 + (lane>>2);
  int growA = w*16 + (lane>>2);
  int gcol8 = (lane&3)*8;

  const int NT1 = CA/32, NT2 = CS/32, NT = NT1+NT2;  // 24+12
  #pragma unroll 1
  for (int t=0; t<NT; ++t){
    const unsigned short* Ap; const unsigned short* Bp; int K, k0;
    if (t < NT1){ Ap=A1; Bp=B1; K=CA; k0=t*32; }
    else        { Ap=A2; Bp=B2; K=CS; k0=(t-NT1)*32; }
    __syncthreads();
    gload_lds16(Ap + (size_t)(m0 + growA)*K + k0 + gcol8, &Ash[(w*16)*32]);
    #pragma unroll
    for (int i=0;i<2;i++){
      int rB = growB + i*16;
      gload_lds16(Bp + (size_t)(n0 + rB)*K + k0 + gcol8, &Bsh[(w*32 + i*16)*32]);
    }
    __syncthreads();

    short8 af[2], bf[4];
    #pragma unroll
    for (int mi=0;mi<2;mi++)
      af[mi] = *(const short8*)&Ash[(mbase + mi*16 + lr)*32 + quad*8];
    #pragma unroll
    for (int ni=0;ni<4;ni++)
      bf[ni] = *(const short8*)&Bsh[(nbase + ni*16 + lr)*32 + quad*8];
    if (t < NT1){
      #pragma unroll
      for (int mi=0;mi<2;mi++)
        #pragma unroll
        for (int ni=0;ni<4;ni++)
          acc1[mi][ni] = __builtin_amdgcn_mfma_f32_16x16x32_bf16(af[mi], bf[ni], acc1[mi][ni], 0,0,0);
    } else {
      #pragma unroll
      for (int mi=0;mi<2;mi++)
        #pragma unroll
        for (int ni=0;ni<4;ni++)
          acc2[mi][ni] = __builtin_amdgcn_mfma_f32_16x16x32_bf16(af[mi], bf[ni], acc2[mi][ni], 0,0,0);
    }
  }

  #pragma unroll
  for (int ni=0;ni<4;ni++){
    int col = n0 + nbase + ni*16 + lr;
    float bv1 = bias1[col];
    float bv2 = bias2[col];
    #pragma unroll
    for (int mi=0;mi<2;mi++){
      #pragma unroll
      for (int reg=0;reg<4;reg++){
        int row = m0 + mbase + mi*16 + quad*4 + reg;
        outp[(size_t)row*CA + col] = sigmoidf_(acc2[mi][ni][reg] + bv2)*(acc1[mi][ni][reg] + bv1);
      }
    }
  }
}

// ---------------- qkvg GEMM, 128x128 m97 structure + XCD swizzle (768 blocks, 3/CU) ----------------
__global__ __launch_bounds__(256) void qkvg_gemm(
  const unsigned short* __restrict__ A1, const unsigned short* __restrict__ B1,
  const float* __restrict__ bias1, unsigned short* __restrict__ outp)
{
  __shared__ unsigned short Ash[128*32];
  __shared__ unsigned short Bsh[128*32];

  int tid = threadIdx.x;
  int w = tid >> 6, lane = tid & 63;
  int lr = lane & 15, quad = lane >> 4;
  int wg = xcd_swz(blockIdx.y*gridDim.x + blockIdx.x, gridDim.x*gridDim.y);
  int bx = wg % gridDim.x, by = wg / gridDim.x;
  int m0 = by*128, n0 = bx*128;
  int mbase = (w&1)*64, nbase = (w>>1)*64;

  float4v acc1[4][4];
  #pragma unroll
  for (int i=0;i<4;i++)
    #pragma unroll
    for (int j=0;j<4;j++)
      acc1[i][j] = (float4v){0.f,0.f,0.f,0.f};

  int grow = w*32 + (lane>>2);
  int gcol8 = (lane&3)*8;

  for (int k0=0; k0<CA; k0+=32){
    __syncthreads();
    #pragma unroll
    for (int i=0;i<2;i++){
      int rA = grow + i*16;
      gload_lds16(A1 + (size_t)(m0 + rA)*CA + k0 + gcol8, &Ash[(w*32 + i*16)*32]);
      gload_lds16(B1 + (size_t)(n0 + rA)*CA + k0 + gcol8, &Bsh[(w*32 + i*16)*32]);
    }
    __syncthreads();

    short8 af[4], bf[4];
    #pragma unroll
    for (int mi=0;mi<4;mi++)
      af[mi] = *(const short8*)&Ash[(mbase + mi*16 + lr)*32 + quad*8];
    #pragma unroll
    for (int ni=0;ni<4;ni++)
      bf[ni] = *(const short8*)&Bsh[(nbase + ni*16 + lr)*32 + quad*8];
    #pragma unroll
    for (int mi=0;mi<4;mi++)
      #pragma unroll
      for (int ni=0;ni<4;ni++)
        acc1[mi][ni] = __builtin_amdgcn_mfma_f32_16x16x32_bf16(af[mi], bf[ni], acc1[mi][ni], 0,0,0);
  }

  #pragma unroll
  for (int ni=0;ni<4;ni++){
    int col = n0 + nbase + ni*16 + lr;
    float bv = bias1[col];
    #pragma unroll
    for (int mi=0;mi<4;mi++){
      #pragma unroll
      for (int reg=0;reg<4;reg++){
        int row = m0 + mbase + mi*16 + quad*4 + reg;
        outp[(size_t)row*3072 + col] = f2bf(acc1[mi][ni][reg] + bv);
      }
    }
  }
}

// ---------------- attention: one wave per (w,h); V staged in LDS ----------------
__global__ __launch_bounds__(256) void attn_kernel(
  const unsigned short* __restrict__ qh,
  const unsigned short* __restrict__ bias3h,
  unsigned short* __restrict__ og)
{
  __shared__ unsigned short Vs[128*192];
  __shared__ unsigned short Pb[4][32*40];
  int tid = threadIdx.x, wave = tid>>6, lane = tid&63;
  int lr = lane&15, quad = lane>>4;
  int w = blockIdx.x, h = blockIdx.y*4 + wave;
  int start = w*NQW - 48;
  const float scale = 0.14433756729740643f;  // 1/sqrt(48)

  // ---- cooperative V staging ----
  {
    int hbase = blockIdx.y*4*DH;
    #pragma unroll
    for (int it=0; it<12; ++it){
      int c = it*256 + tid;
      int key = c/24, cc = c - key*24;
      int kr = min(max(start+key,0),N_TOK-1);
      short8 v = *(const short8*)&qh[(size_t)kr*3072 + 1536 + hbase + cc*8];
      int cs = cc ^ (((key>>3)&3)*2);
      *(short8*)&Vs[key*192 + cs*8] = v;
    }
  }

  short8 zero8 = {0,0,0,0,0,0,0,0};

  // ---- Q A-frags ----
  short8 aq[2][2];
  #pragma unroll
  for (int mt=0;mt<2;mt++){
    int row = w*NQW + mt*16 + lr;
    const unsigned short* qp = qh + (size_t)row*3072 + h*DH;
    aq[mt][0] = *(const short8*)(qp + quad*8);
    aq[mt][1] = (quad<2) ? *(const short8*)(qp + 32 + quad*8) : zero8;
  }

  // ---- QK^T ----
  float4v c[2][8];
  #pragma unroll
  for (int mt=0;mt<2;mt++)
    #pragma unroll
    for (int nt=0;nt<8;nt++) c[mt][nt] = (float4v){0.f,0.f,0.f,0.f};

  #pragma unroll 2
  for (int nt=0;nt<8;nt++){
    int krc = min(max(start + nt*16 + lr,0),N_TOK-1);
    const unsigned short* kp = qh + (size_t)krc*3072 + 768 + h*DH;
    short8 bk0 = *(const short8*)(kp + quad*8);
    short8 bk1 = (quad<2) ? *(const short8*)(kp + 32 + quad*8) : zero8;
    #pragma unroll
    for (int mt=0;mt<2;mt++){
      c[mt][nt] = __builtin_amdgcn_mfma_f32_16x16x32_bf16(aq[mt][0], bk0, c[mt][nt], 0,0,0);
      c[mt][nt] = __builtin_amdgcn_mfma_f32_16x16x32_bf16(aq[mt][1], bk1, c[mt][nt], 0,0,0);
    }
  }

  // ---- bias + mask + softmax in registers ----
  float rmax[2][4], rsum[2][4];
  #pragma unroll
  for (int mt=0;mt<2;mt++)
    #pragma unroll
    for (int r=0;r<4;r++){ rmax[mt][r] = -3.0e38f; rsum[mt][r] = 0.f; }

  #pragma unroll
  for (int nt=0;nt<8;nt++){
    int key = start + nt*16 + lr;
    bool valid = (key>=0) && (key<N_TOK);
    #pragma unroll
    for (int mt=0;mt<2;mt++){
      #pragma unroll
      for (int r=0;r<4;r++){
        int q = mt*16 + quad*4 + r;
        float bv = bf2f(bias3h[(((size_t)(w*NQW+q))*NHEAD + h)*128 + nt*16 + lr]);
        float v = valid ? (c[mt][nt][r]*scale + bv) : -1e9f;
        c[mt][nt][r] = v;
        rmax[mt][r] = fmaxf(rmax[mt][r], v);
      }
    }
  }
  #pragma unroll
  for (int mt=0;mt<2;mt++)
    #pragma unroll
    for (int r=0;r<4;r++){
      float m = rmax[mt][r];
      m = fmaxf(m, __shfl_xor(m,1)); m = fmaxf(m, __shfl_xor(m,2));
      m = fmaxf(m, __shfl_xor(m,4)); m = fmaxf(m, __shfl_xor(m,8));
      rmax[mt][r] = m;
    }
  #pragma unroll
  for (int nt=0;nt<8;nt++)
    #pragma unroll
    for (int mt=0;mt<2;mt++)
      #pragma unroll
      for (int r=0;r<4;r++){
        float e = __expf(c[mt][nt][r] - rmax[mt][r]);
        c[mt][nt][r] = e;
        rsum[mt][r] += e;
      }
  #pragma unroll
  for (int mt=0;mt<2;mt++)
    #pragma unroll
    for (int r=0;r<4;r++){
      float sv = rsum[mt][r];
      sv += __shfl_xor(sv,1); sv += __shfl_xor(sv,2);
      sv += __shfl_xor(sv,4); sv += __shfl_xor(sv,8);
      rsum[mt][r] = 1.f/sv;
    }

  __syncthreads();   // Vs staged by all waves

  // ---- PV ----
  unsigned short* ph = &Pb[wave][0];
  float4v o[2][3];
  #pragma unroll
  for (int mt=0;mt<2;mt++)
    #pragma unroll
    for (int no=0;no<3;no++) o[mt][no] = (float4v){0.f,0.f,0.f,0.f};

  #pragma unroll 1
  for (int c2=0;c2<2;c2++){
    #pragma unroll 1
    for (int ks=0;ks<2;ks++){
      int ntb = c2*4 + ks*2;
      #pragma unroll
      for (int t=0;t<2;t++){
        int nt = ntb + t;
        #pragma unroll
        for (int mt=0;mt<2;mt++){
          #pragma unroll
          for (int r=0;r<4;r++){
            int q = mt*16 + quad*4 + r;
            ph[q*40 + t*16 + lr] = f2bf(c[mt][nt][r]*rsum[mt][r]);
          }
        }
      }
      short8 pa[2];
      #pragma unroll
      for (int mt=0;mt<2;mt++)
        pa[mt] = *(const short8*)&ph[(mt*16+lr)*40 + quad*8];
      #pragma unroll
      for (int no=0;no<3;no++){
        union { short8 v; unsigned short u[8]; } V;
        int col = wave*DH + no*16 + lr;
        int chunk = col >> 3;
        int cs = (chunk ^ (quad*2))*8 + (col & 7);
        #pragma unroll
        for (int j=0;j<8;j++){
          int key = c2*64 + ks*32 + quad*8 + j;
          V.u[j] = Vs[key*192 + cs];
        }
        #pragma unroll
        for (int mt=0;mt<2;mt++)
          o[mt][no] = __builtin_amdgcn_mfma_f32_16x16x32_bf16(pa[mt], V.v, o[mt][no], 0,0,0);
      }
    }
  }

  // ---- epilogue ----
  #pragma unroll
  for (int mt=0;mt<2;mt++){
    #pragma unroll
    for (int no=0;no<3;no++){
      int d = no*16 + lr;
      #pragma unroll
      for (int r=0;r<4;r++){
        int q = mt*16 + quad*4 + r;
        size_t grow = (size_t)(w*NQW + q);
        float g = bf2f(qh[grow*3072 + 2304 + h*DH + d]);
        og[grow*CA + h*DH + d] = f2bf(o[mt][no][r] * sigmoidf_(g));
      }
    }
  }
}

extern "C" void kernel_launch(void* const* d_in, const int* in_sizes, int n_in,
                              void* d_out, int out_size, void* d_ws, size_t ws_size,
                              hipStream_t stream)
{
  const float* a            = (const float*)d_in[0];
  const float* s            = (const float*)d_in[1];
  const float* z            = (const float*)d_in[2];
  const float* adaln_gamma  = (const float*)d_in[3];
  const float* adaln_ws     = (const float*)d_in[4];
  const float* adaln_bs     = (const float*)d_in[5];
  const float* adaln_wskip  = (const float*)d_in[6];
  const float* lnz_gamma    = (const float*)d_in[7];
  const float* wz           = (const float*)d_in[8];
  const float* wq           = (const float*)d_in[9];
  const float* bq           = (const float*)d_in[10];
  const float* wk           = (const float*)d_in[11];
  const float* wv           = (const float*)d_in[12];
  const float* wg           = (const float*)d_in[13];
  const float* bg           = (const float*)d_in[14];
  const float* wo           = (const float*)d_in[15];
  const float* bo           = (const float*)d_in[16];
  const float* w_last       = (const float*)d_in[17];
  const float* b_last       = (const float*)d_in[18];
  float* out = (float*)d_out;

  char* base = (char*)d_ws;
  size_t off = 0;
  auto alloc = [&](size_t bytes)->char*{ char* p = base + off; off += (bytes + 255) & ~(size_t)255; return p; };

  unsigned short* s_ln_h = (unsigned short*)alloc((size_t)N_TOK*CS*2);
  unsigned short* s_h    = (unsigned short*)alloc((size_t)N_TOK*CS*2);
  float*          a_n    = (float*)alloc((size_t)N_TOK*CA*4);
  unsigned short* a_ln_h = (unsigned short*)alloc((size_t)N_TOK*CA*2);
  unsigned short* og_h   = (unsigned short*)alloc((size_t)N_TOK*CA*2);
  unsigned short* Wt1    = (unsigned short*)alloc((size_t)1536*CS*2);
  unsigned short* Wt2    = (unsigned short*)alloc((size_t)3072*CA*2);
  unsigned short* Wt3    = (unsigned short*)alloc((size_t)CA*CA*2);
  unsigned short* Wt4    = (unsigned short*)alloc((size_t)CA*CS*2);
  unsigned short* bias3h = (unsigned short*)alloc((size_t)N_TOK*NHEAD*NKW*2);
  unsigned short* qkvg_h = (unsigned short*)alloc((size_t)N_TOK*3072*2);
  float*          biasq  = (float*)alloc((size_t)3072*4);

  prep_zbias_kernel<<<dim3(2048+1024+1024+936+12), 256, 0, stream>>>(
      z, lnz_gamma, wz, bias3h,
      s, adaln_gamma, s_ln_h, s_h, a, a_n,
      adaln_ws, adaln_wskip, wq, wk, wv, wg, wo, w_last,
      Wt1, Wt2, Wt3, Wt4, bq, bg, biasq);

  adaln_gemm<<<dim3(CA/128, N_TOK/64), 256, 0, stream>>>(s_ln_h, Wt1, adaln_bs, a_n, a_ln_h);

  qkvg_gemm<<<dim3(3072/128, N_TOK/128), 256, 0, stream>>>(a_ln_h, Wt2, biasq, qkvg_h);

  attn_kernel<<<dim3(NBLK, 4), 256, 0, stream>>>(qkvg_h, bias3h, og_h);

  final_gemm<<<dim3(CA/128, N_TOK/64), 256, 0, stream>>>(
      og_h, Wt3, bo, s_h, Wt4, b_last, out);
}

// Round 12
// 217.529 us; speedup vs baseline: 1.1618x; 1.0159x over previous
//
#include <hip/hip_runtime.h>
#include <hip/hip_bf16.h>
#include <math.h>

#define N_TOK 4096
#define CA 768
#define CS 384
#define CZ 128
#define NHEAD 16
#define DH 48
#define NQW 32
#define NKW 128
#define NBLK 128

typedef __attribute__((ext_vector_type(8))) short short8;
typedef __attribute__((ext_vector_type(4))) float float4v;
typedef __attribute__((ext_vector_type(4))) unsigned short ushort4v;

__device__ __forceinline__ float sigmoidf_(float x){ return 1.0f/(1.0f+__expf(-x)); }

__device__ __forceinline__ unsigned short f2bf(float x){
  unsigned u = __float_as_uint(x);
  unsigned r = (u + 0x7FFFu + ((u>>16)&1u)) >> 16;
  return (unsigned short)r;
}
__device__ __forceinline__ float bf2f(unsigned short b){
  return __uint_as_float(((unsigned)b)<<16);
}
__device__ __forceinline__ short8 cvt8(const float* xv){
  union { short8 v; unsigned short u[8]; } H;
  #pragma unroll
  for (int j=0;j<8;j++) H.u[j] = f2bf(xv[j]);
  return H.v;
}
// RNE pack via HW instruction (same bits as f2bf for finite inputs)
__device__ __forceinline__ short8 cvt8pk(const float* x){
  union { short8 v; unsigned u32[4]; } H;
  #pragma unroll
  for (int i=0;i<4;i++)
    asm("v_cvt_pk_bf16_f32 %0, %1, %2" : "=v"(H.u32[i]) : "v"(x[2*i]), "v"(x[2*i+1]));
  return H.v;
}

__device__ __forceinline__ void gload_lds16(const void* gsrc, void* ldst){
  __builtin_amdgcn_global_load_lds(
    (const __attribute__((address_space(1))) void*)gsrc,
    (__attribute__((address_space(3))) void*)ldst, 16, 0, 0);
}

// bijective XCD swizzle (nwg % 8 == 0)
__device__ __forceinline__ int xcd_swz(int wg, int nwg){
  int cpx = nwg >> 3;
  return (wg & 7)*cpx + (wg >> 3);
}

// ---------------- merged prep + zbias (32KB LDS union -> 5 blocks/CU) ----------------
// [0,2048): zbias (2 groups each, waves 0-1) ; +1024 ln_s ; +1024 ln_a ; +936 cvtT ; +12 biasq
__global__ __launch_bounds__(256) void prep_zbias_kernel(
  const float* __restrict__ z, const float* __restrict__ lnz_gamma,
  const float* __restrict__ wz, unsigned short* __restrict__ bias3,
  const float* __restrict__ s, const float* __restrict__ adaln_gamma,
  unsigned short* __restrict__ s_ln_h, unsigned short* __restrict__ s_h,
  const float* __restrict__ a, float* __restrict__ a_n,
  const float* __restrict__ ws, const float* __restrict__ wskip,
  const float* __restrict__ wq, const float* __restrict__ wk,
  const float* __restrict__ wv, const float* __restrict__ wg,
  const float* __restrict__ wo, const float* __restrict__ wlast,
  unsigned short* __restrict__ Wt1, unsigned short* __restrict__ Wt2,
  unsigned short* __restrict__ Wt3, unsigned short* __restrict__ Wt4,
  const float* __restrict__ bq, const float* __restrict__ bg,
  float* __restrict__ biasq)
{
  union PZ {
    float tile[64][65];       // 16.6 KB
    float zbuf[2][2][2048];   // 32 KB (2 zbias waves, dbuf)
  };
  __shared__ PZ sm;
  int bid = blockIdx.x;
  int tid = threadIdx.x;

  if (bid < 2048){
    // ================= zbias (waves 0,1 only) =================
    int wave = tid>>6, lane = tid&63;
    if (wave >= 2) return;
    int lr = lane&15, quad = lane>>4;

    short8 bwh[4];
    float w1 = 0.f;
    #pragma unroll
    for (int ks=0;ks<4;ks++){
      float wv_[8];
      #pragma unroll
      for (int j=0;j<8;j++){
        int k = ks*32 + quad*8 + j;
        wv_[j] = wz[k*NHEAD + lr]*lnz_gamma[k];
        w1 += wv_[j];
      }
      bwh[ks] = cvt8pk(wv_);
    }
    w1 += __shfl_xor(w1, 16);
    w1 += __shfl_xor(w1, 32);

    size_t group = (size_t)bid*2 + wave;   // 0..4095
    const float* zg = z + group*(size_t)(NKW*CZ);
    unsigned short* outg = bias3 + group*2048;

    int rsub = lane>>5;
    int csw  = lane&31;
    auto stage = [&](int buf, int b){
      #pragma unroll
      for (int i=0;i<8;i++){
        int r  = 2*i + rsub;
        int gc = csw ^ (r & 7);
        gload_lds16(zg + (size_t)(b*16 + r)*CZ + gc*4, &sm.zbuf[wave][buf][i*256]);
      }
    };

    stage(0, 0);
    int buf = 0;
    #pragma unroll 1
    for (int b=0; b<8; ++b){
      if (b < 7){
        stage(buf^1, b+1);
        asm volatile("s_waitcnt vmcnt(8)" ::: "memory");
      } else {
        asm volatile("s_waitcnt vmcnt(0)" ::: "memory");
      }
      __builtin_amdgcn_sched_barrier(0);

      const float* rowp = &sm.zbuf[wave][buf][lr*128];
      int sswz = lr & 7;
      float4 p[8];
      #pragma unroll
      for (int ks=0;ks<4;ks++){
        int c0 = ks*8 + quad*2;
        p[ks*2]   = *(const float4*)(rowp + (size_t)((c0  )^sswz)*4);
        p[ks*2+1] = *(const float4*)(rowp + (size_t)((c0+1)^sswz)*4);
      }
      float sum=0.f, sq=0.f;
      #pragma unroll
      for (int t=0;t<8;t++){
        sum += p[t].x + p[t].y + p[t].z + p[t].w;
        sq  += p[t].x*p[t].x + p[t].y*p[t].y + p[t].z*p[t].z + p[t].w*p[t].w;
      }
      sum += __shfl_xor(sum,16); sum += __shfl_xor(sum,32);
      sq  += __shfl_xor(sq,16);  sq  += __shfl_xor(sq,32);
      float mean = sum*(1.f/CZ);
      float var  = sq*(1.f/CZ) - mean*mean;
      float rs = rsqrtf(var + 1e-5f);

      float4v c = (float4v){0.f,0.f,0.f,0.f};
      #pragma unroll
      for (int ks=0;ks<4;ks++){
        float xv[8];
        xv[0]=p[ks*2].x;   xv[1]=p[ks*2].y;   xv[2]=p[ks*2].z;   xv[3]=p[ks*2].w;
        xv[4]=p[ks*2+1].x; xv[5]=p[ks*2+1].y; xv[6]=p[ks*2+1].z; xv[7]=p[ks*2+1].w;
        c = __builtin_amdgcn_mfma_f32_16x16x32_bf16(cvt8pk(xv), bwh[ks], c, 0,0,0);
      }

      ushort4v o4;
      #pragma unroll
      for (int r=0;r<4;r++){
        int rrow = quad*4 + r;
        float m_r  = __shfl(mean, rrow);
        float rs_r = __shfl(rs, rrow);
        o4[r] = f2bf(rs_r*(c[r] - m_r*w1));
      }
      *(ushort4v*)(outg + lr*128 + b*16 + quad*4) = o4;
      buf ^= 1;
    }
    return;
  }
  bid -= 2048;

  if (bid < 1024){
    // ================= ln_s =================
    int wave = tid>>6, lane = tid&63;
    int row = bid*4 + wave;
    const float* x = s + (size_t)row*CS;
    float v[6]; float sum=0.f, sq=0.f;
    #pragma unroll
    for (int i=0;i<6;i++){ v[i]=x[lane+64*i]; sum+=v[i]; sq+=v[i]*v[i]; }
    #pragma unroll
    for (int off=32; off; off>>=1){ sum+=__shfl_xor(sum,off); sq+=__shfl_xor(sq,off); }
    float m = sum*(1.f/CS);
    float var = sq*(1.f/CS)-m*m;
    float rs = rsqrtf(var+1e-5f);
    #pragma unroll
    for (int i=0;i<6;i++){
      int c = lane+64*i;
      s_ln_h[(size_t)row*CS+c] = f2bf((v[i]-m)*rs*adaln_gamma[c]);
      s_h[(size_t)row*CS+c]    = f2bf(v[i]);
    }
    return;
  }
  bid -= 1024;

  if (bid < 1024){
    // ================= ln_a =================
    int wave = tid>>6, lane = tid&63;
    int row = bid*4 + wave;
    const float* x = a + (size_t)row*CA;
    float v[12]; float sum=0.f, sq=0.f;
    #pragma unroll
    for (int i=0;i<12;i++){ v[i]=x[lane+64*i]; sum+=v[i]; sq+=v[i]*v[i]; }
    #pragma unroll
    for (int off=32; off; off>>=1){ sum+=__shfl_xor(sum,off); sq+=__shfl_xor(sq,off); }
    float m = sum*(1.f/CA);
    float var = sq*(1.f/CA)-m*m;
    float rs = rsqrtf(var+1e-5f);
    float* o = a_n + (size_t)row*CA;
    #pragma unroll
    for (int i=0;i<12;i++) o[lane+64*i] = (v[i]-m)*rs;
    return;
  }
  bid -= 1024;

  if (bid < 936){
    // ================= weight transpose+cvt =================
    const float* src; unsigned short* dst; int K; int local;
    if      (bid < 72)  { src=ws;    dst=Wt1;                   K=CS; local=bid; }
    else if (bid < 144) { src=wskip; dst=Wt1 + (size_t)768*CS;  K=CS; local=bid-72; }
    else if (bid < 288) { src=wq;    dst=Wt2;                   K=CA; local=bid-144; }
    else if (bid < 432) { src=wk;    dst=Wt2 + (size_t)768*CA;  K=CA; local=bid-288; }
    else if (bid < 576) { src=wv;    dst=Wt2 + (size_t)1536*CA; K=CA; local=bid-432; }
    else if (bid < 720) { src=wg;    dst=Wt2 + (size_t)2304*CA; K=CA; local=bid-576; }
    else if (bid < 864) { src=wo;    dst=Wt3;                   K=CA; local=bid-720; }
    else                { src=wlast; dst=Wt4;                   K=CS; local=bid-864; }
    int ktiles = K/64;
    int kb = (local % ktiles)*64, nb = (local / ktiles)*64;
    int c = tid & 63, r0 = tid >> 6;
    #pragma unroll
    for (int i=0;i<16;i++){
      int r = r0 + 4*i;
      sm.tile[r][c] = src[(size_t)(kb+r)*CA + nb + c];
    }
    __syncthreads();
    #pragma unroll
    for (int i=0;i<16;i++){
      int r = r0 + 4*i;          // n-local
      dst[(size_t)(nb+r)*K + kb + c] = f2bf(sm.tile[c][r]);
    }
    return;
  }
  bid -= 936;

  // ================= biasq =================
  int i = bid*256 + tid;
  float v = 0.f;
  if (i < 768) v = bq[i];
  else if (i >= 2304) v = bg[i-2304];
  biasq[i] = v;
}

// ---------------- adaln GEMM, 64x128 tile, BK=64 + XOR chunk swizzle ----------------
// a_ln = sigmoid(s_ln@ws + bs)*a_n + s_ln@wskip -> bf16
__global__ __launch_bounds__(256) void adaln_gemm(
  const unsigned short* __restrict__ A, const unsigned short* __restrict__ Bt,
  const float* __restrict__ bs, const float* __restrict__ a_n,
  unsigned short* __restrict__ outh)
{
  __shared__ unsigned short Ash[64*64];
  __shared__ unsigned short B1sh[128*64];
  __shared__ unsigned short B2sh[128*64];

  int tid = threadIdx.x;
  int w = tid >> 6, lane = tid & 63;
  int lr = lane & 15, quad = lane >> 4;
  int wg = xcd_swz(blockIdx.y*gridDim.x + blockIdx.x, gridDim.x*gridDim.y);
  int bx = wg % gridDim.x, by = wg / gridDim.x;
  int m0 = by*64, n0 = bx*128;
  int mbase = (w&1)*32, nbase = (w>>1)*64;

  float4v acc1[2][4], acc2[2][4];
  #pragma unroll
  for (int i=0;i<2;i++)
    #pragma unroll
    for (int j=0;j<4;j++){
      acc1[i][j] = (float4v){0.f,0.f,0.f,0.f};
      acc2[i][j] = (float4v){0.f,0.f,0.f,0.f};
    }

  int rsub = lane>>3;              // row within 8-row issue (0..7)
  int gcs  = ((lane&7) ^ rsub)*8;  // swizzled source chunk (ushorts)
  int rkey = lr & 7;               // read-side XOR key

  for (int k0=0; k0<CS; k0+=64){
    __syncthreads();
    #pragma unroll
    for (int it=0; it<2; ++it){    // A: 64 rows
      int r = it*32 + w*8 + rsub;
      gload_lds16(A + (size_t)(m0 + r)*CS + k0 + gcs, &Ash[(it*32 + w*8)*64]);
    }
    #pragma unroll
    for (int it=0; it<4; ++it){    // B1,B2: 128 rows each
      int r = it*32 + w*8 + rsub;
      gload_lds16(Bt + (size_t)(n0 + r)*CS + k0 + gcs, &B1sh[(it*32 + w*8)*64]);
      gload_lds16(Bt + (size_t)(768 + n0 + r)*CS + k0 + gcs, &B2sh[(it*32 + w*8)*64]);
    }
    __syncthreads();

    #pragma unroll
    for (int ks=0; ks<2; ++ks){
      int slot = ((ks*4 + quad) ^ rkey)*8;
      short8 af[2], b1f[4], b2f[4];
      #pragma unroll
      for (int mi=0;mi<2;mi++)
        af[mi] = *(const short8*)&Ash[(mbase + mi*16 + lr)*64 + slot];
      #pragma unroll
      for (int ni=0;ni<4;ni++){
        b1f[ni] = *(const short8*)&B1sh[(nbase + ni*16 + lr)*64 + slot];
        b2f[ni] = *(const short8*)&B2sh[(nbase + ni*16 + lr)*64 + slot];
      }
      #pragma unroll
      for (int mi=0;mi<2;mi++)
        #pragma unroll
        for (int ni=0;ni<4;ni++){
          acc1[mi][ni] = __builtin_amdgcn_mfma_f32_16x16x32_bf16(af[mi], b1f[ni], acc1[mi][ni], 0,0,0);
          acc2[mi][ni] = __builtin_amdgcn_mfma_f32_16x16x32_bf16(af[mi], b2f[ni], acc2[mi][ni], 0,0,0);
        }
    }
  }

  #pragma unroll
  for (int ni=0;ni<4;ni++){
    int col = n0 + nbase + ni*16 + lr;
    float bsv = bs[col];
    #pragma unroll
    for (int mi=0;mi<2;mi++){
      #pragma unroll
      for (int reg=0;reg<4;reg++){
        int row = m0 + mbase + mi*16 + quad*4 + reg;
        float v = sigmoidf_(acc1[mi][ni][reg] + bsv)*a_n[(size_t)row*CA + col] + acc2[mi][ni][reg];
        outh[(size_t)row*CA + col] = f2bf(v);
      }
    }
  }
}

// ---------------- final dual-K GEMM, 64x128 tile, BK=64 + XOR chunk swizzle ----------------
// out = sigmoid(s@wlast+blast) * (og@wo+bo)  (f32 out)
__global__ __launch_bounds__(256) void final_gemm(
  const unsigned short* __restrict__ A1, const unsigned short* __restrict__ B1,
  const float* __restrict__ bias1,
  const unsigned short* __restrict__ A2, const unsigned short* __restrict__ B2,
  const float* __restrict__ bias2,
  float* __restrict__ outp)
{
  __shared__ unsigned short Ash[64*64];
  __shared__ unsigned short Bsh[128*64];

  int tid = threadIdx.x;
  int w = tid >> 6, lane = tid & 63;
  int lr = lane & 15, quad = lane >> 4;
  int wg = xcd_swz(blockIdx.y*gridDim.x + blockIdx.x, gridDim.x*gridDim.y);
  int bx = wg % gridDim.x, by = wg / gridDim.x;
  int m0 = by*64, n0 = bx*128;
  int mbase = (w&1)*32, nbase = (w>>1)*64;

  float4v acc1[2][4], acc2[2][4];
  #pragma unroll
  for (int i=0;i<2;i++)
    #pragma unroll
    for (int j=0;j<4;j++){
      acc1[i][j] = (float4v){0.f,0.f,0.f,0.f};
      acc2[i][j] = (float4v){0.f,0.f,0.f,0.f};
    }

  int rsub = lane>>3;
  int gcs  = ((lane&7) ^ rsub)*8;
  int rkey = lr & 7;

  const int NT1 = CA/64, NT2 = CS/64, NT = NT1+NT2;  // 12+6
  #pragma unroll 1
  for (int t=0; t<NT; ++t){
    const unsigned short* Ap; const unsigned short* Bp; int K, k0;
    if (t < NT1){ Ap=A1; Bp=B1; K=CA; k0=t*64; }
    else        { Ap=A2; Bp=B2; K=CS; k0=(t-NT1)*64; }
    __syncthreads();
    #pragma unroll
    for (int it=0; it<2; ++it){
      int r = it*32 + w*8 + rsub;
      gload_lds16(Ap + (size_t)(m0 + r)*K + k0 + gcs, &Ash[(it*32 + w*8)*64]);
    }
    #pragma unroll
    for (int it=0; it<4; ++it){
      int r = it*32 + w*8 + rsub;
      gload_lds16(Bp + (size_t)(n0 + r)*K + k0 + gcs, &Bsh[(it*32 + w*8)*64]);
    }
    __syncthreads();

    #pragma unroll
    for (int ks=0; ks<2; ++ks){
      int slot = ((ks*4 + quad) ^ rkey)*8;
      short8 af[2], bf[4];
      #pragma unroll
      for (int mi=0;mi<2;mi++)
        af[mi] = *(const short8*)&Ash[(mbase + mi*16 + lr)*64 + slot];
      #pragma unroll
      for (int ni=0;ni<4;ni++)
        bf[ni] = *(const short8*)&Bsh[(nbase + ni*16 + lr)*64 + slot];
      if (t < NT1){
        #pragma unroll
        for (int mi=0;mi<2;mi++)
          #pragma unroll
          for (int ni=0;ni<4;ni++)
            acc1[mi][ni] = __builtin_amdgcn_mfma_f32_16x16x32_bf16(af[mi], bf[ni], acc1[mi][ni], 0,0,0);
      } else {
        #pragma unroll
        for (int mi=0;mi<2;mi++)
          #pragma unroll
          for (int ni=0;ni<4;ni++)
            acc2[mi][ni] = __builtin_amdgcn_mfma_f32_16x16x32_bf16(af[mi], bf[ni], acc2[mi][ni], 0,0,0);
      }
    }
  }

  #pragma unroll
  for (int ni=0;ni<4;ni++){
    int col = n0 + nbase + ni*16 + lr;
    float bv1 = bias1[col];
    float bv2 = bias2[col];
    #pragma unroll
    for (int mi=0;mi<2;mi++){
      #pragma unroll
      for (int reg=0;reg<4;reg++){
        int row = m0 + mbase + mi*16 + quad*4 + reg;
        outp[(size_t)row*CA + col] = sigmoidf_(acc2[mi][ni][reg] + bv2)*(acc1[mi][ni][reg] + bv1);
      }
    }
  }
}

// ---------------- qkvg GEMM, 128x128 tile, BK=64 + XOR chunk swizzle ----------------
__global__ __launch_bounds__(256) void qkvg_gemm(
  const unsigned short* __restrict__ A1, const unsigned short* __restrict__ B1,
  const float* __restrict__ bias1, unsigned short* __restrict__ outp)
{
  __shared__ unsigned short Ash[128*64];
  __shared__ unsigned short Bsh[128*64];

  int tid = threadIdx.x;
  int w = tid >> 6, lane = tid & 63;
  int lr = lane & 15, quad = lane >> 4;
  int wg = xcd_swz(blockIdx.y*gridDim.x + blockIdx.x, gridDim.x*gridDim.y);
  int bx = wg % gridDim.x, by = wg / gridDim.x;
  int m0 = by*128, n0 = bx*128;
  int mbase = (w&1)*64, nbase = (w>>1)*64;

  float4v acc1[4][4];
  #pragma unroll
  for (int i=0;i<4;i++)
    #pragma unroll
    for (int j=0;j<4;j++)
      acc1[i][j] = (float4v){0.f,0.f,0.f,0.f};

  int rsub = lane>>3;
  int gcs  = ((lane&7) ^ rsub)*8;
  int rkey = lr & 7;

  for (int k0=0; k0<CA; k0+=64){
    __syncthreads();
    #pragma unroll
    for (int it=0; it<4; ++it){
      int r = it*32 + w*8 + rsub;
      gload_lds16(A1 + (size_t)(m0 + r)*CA + k0 + gcs, &Ash[(it*32 + w*8)*64]);
      gload_lds16(B1 + (size_t)(n0 + r)*CA + k0 + gcs, &Bsh[(it*32 + w*8)*64]);
    }
    __syncthreads();

    #pragma unroll
    for (int ks=0; ks<2; ++ks){
      int slot = ((ks*4 + quad) ^ rkey)*8;
      short8 af[4], bf[4];
      #pragma unroll
      for (int mi=0;mi<4;mi++)
        af[mi] = *(const short8*)&Ash[(mbase + mi*16 + lr)*64 + slot];
      #pragma unroll
      for (int ni=0;ni<4;ni++)
        bf[ni] = *(const short8*)&Bsh[(nbase + ni*16 + lr)*64 + slot];
      #pragma unroll
      for (int mi=0;mi<4;mi++)
        #pragma unroll
        for (int ni=0;ni<4;ni++)
          acc1[mi][ni] = __builtin_amdgcn_mfma_f32_16x16x32_bf16(af[mi], bf[ni], acc1[mi][ni], 0,0,0);
    }
  }

  #pragma unroll
  for (int ni=0;ni<4;ni++){
    int col = n0 + nbase + ni*16 + lr;
    float bv = bias1[col];
    #pragma unroll
    for (int mi=0;mi<4;mi++){
      #pragma unroll
      for (int reg=0;reg<4;reg++){
        int row = m0 + mbase + mi*16 + quad*4 + reg;
        outp[(size_t)row*3072 + col] = f2bf(acc1[mi][ni][reg] + bv);
      }
    }
  }
}

// ---------------- attention: one wave per (w,h); V staged in LDS ----------------
__global__ __launch_bounds__(256) void attn_kernel(
  const unsigned short* __restrict__ qh,
  const unsigned short* __restrict__ bias3h,
  unsigned short* __restrict__ og)
{
  __shared__ unsigned short Vs[128*192];
  __shared__ unsigned short Pb[4][32*40];
  int tid = threadIdx.x, wave = tid>>6, lane = tid&63;
  int lr = lane&15, quad = lane>>4;
  int w = blockIdx.x, h = blockIdx.y*4 + wave;
  int start = w*NQW - 48;
  const float scale = 0.14433756729740643f;  // 1/sqrt(48)

  // ---- cooperative V staging ----
  {
    int hbase = blockIdx.y*4*DH;
    #pragma unroll
    for (int it=0; it<12; ++it){
      int c = it*256 + tid;
      int key = c/24, cc = c - key*24;
      int kr = min(max(start+key,0),N_TOK-1);
      short8 v = *(const short8*)&qh[(size_t)kr*3072 + 1536 + hbase + cc*8];
      int cs = cc ^ (((key>>3)&3)*2);
      *(short8*)&Vs[key*192 + cs*8] = v;
    }
  }

  short8 zero8 = {0,0,0,0,0,0,0,0};

  // ---- Q A-frags ----
  short8 aq[2][2];
  #pragma unroll
  for (int mt=0;mt<2;mt++){
    int row = w*NQW + mt*16 + lr;
    const unsigned short* qp = qh + (size_t)row*3072 + h*DH;
    aq[mt][0] = *(const short8*)(qp + quad*8);
    aq[mt][1] = (quad<2) ? *(const short8*)(qp + 32 + quad*8) : zero8;
  }

  // ---- QK^T ----
  float4v c[2][8];
  #pragma unroll
  for (int mt=0;mt<2;mt++)
    #pragma unroll
    for (int nt=0;nt<8;nt++) c[mt][nt] = (float4v){0.f,0.f,0.f,0.f};

  #pragma unroll 2
  for (int nt=0;nt<8;nt++){
    int krc = min(max(start + nt*16 + lr,0),N_TOK-1);
    const unsigned short* kp = qh + (size_t)krc*3072 + 768 + h*DH;
    short8 bk0 = *(const short8*)(kp + quad*8);
    short8 bk1 = (quad<2) ? *(const short8*)(kp + 32 + quad*8) : zero8;
    #pragma unroll
    for (int mt=0;mt<2;mt++){
      c[mt][nt] = __builtin_amdgcn_mfma_f32_16x16x32_bf16(aq[mt][0], bk0, c[mt][nt], 0,0,0);
      c[mt][nt] = __builtin_amdgcn_mfma_f32_16x16x32_bf16(aq[mt][1], bk1, c[mt][nt], 0,0,0);
    }
  }

  // ---- bias + mask + softmax in registers ----
  float rmax[2][4], rsum[2][4];
  #pragma unroll
  for (int mt=0;mt<2;mt++)
    #pragma unroll
    for (int r=0;r<4;r++){ rmax[mt][r] = -3.0e38f; rsum[mt][r] = 0.f; }

  #pragma unroll
  for (int nt=0;nt<8;nt++){
    int key = start + nt*16 + lr;
    bool valid = (key>=0) && (key<N_TOK);
    #pragma unroll
    for (int mt=0;mt<2;mt++){
      #pragma unroll
      for (int r=0;r<4;r++){
        int q = mt*16 + quad*4 + r;
        float bv = bf2f(bias3h[(((size_t)(w*NQW+q))*NHEAD + h)*128 + nt*16 + lr]);
        float v = valid ? (c[mt][nt][r]*scale + bv) : -1e9f;
        c[mt][nt][r] = v;
        rmax[mt][r] = fmaxf(rmax[mt][r], v);
      }
    }
  }
  #pragma unroll
  for (int mt=0;mt<2;mt++)
    #pragma unroll
    for (int r=0;r<4;r++){
      float m = rmax[mt][r];
      m = fmaxf(m, __shfl_xor(m,1)); m = fmaxf(m, __shfl_xor(m,2));
      m = fmaxf(m, __shfl_xor(m,4)); m = fmaxf(m, __shfl_xor(m,8));
      rmax[mt][r] = m;
    }
  #pragma unroll
  for (int nt=0;nt<8;nt++)
    #pragma unroll
    for (int mt=0;mt<2;mt++)
      #pragma unroll
      for (int r=0;r<4;r++){
        float e = __expf(c[mt][nt][r] - rmax[mt][r]);
        c[mt][nt][r] = e;
        rsum[mt][r] += e;
      }
  #pragma unroll
  for (int mt=0;mt<2;mt++)
    #pragma unroll
    for (int r=0;r<4;r++){
      float sv = rsum[mt][r];
      sv += __shfl_xor(sv,1); sv += __shfl_xor(sv,2);
      sv += __shfl_xor(sv,4); sv += __shfl_xor(sv,8);
      rsum[mt][r] = 1.f/sv;
    }

  __syncthreads();   // Vs staged by all waves

  // ---- PV ----
  unsigned short* ph = &Pb[wave][0];
  float4v o[2][3];
  #pragma unroll
  for (int mt=0;mt<2;mt++)
    #pragma unroll
    for (int no=0;no<3;no++) o[mt][no] = (float4v){0.f,0.f,0.f,0.f};

  #pragma unroll 1
  for (int c2=0;c2<2;c2++){
    #pragma unroll 1
    for (int ks=0;ks<2;ks++){
      int ntb = c2*4 + ks*2;
      #pragma unroll
      for (int t=0;t<2;t++){
        int nt = ntb + t;
        #pragma unroll
        for (int mt=0;mt<2;mt++){
          #pragma unroll
          for (int r=0;r<4;r++){
            int q = mt*16 + quad*4 + r;
            ph[q*40 + t*16 + lr] = f2bf(c[mt][nt][r]*rsum[mt][r]);
          }
        }
      }
      short8 pa[2];
      #pragma unroll
      for (int mt=0;mt<2;mt++)
        pa[mt] = *(const short8*)&ph[(mt*16+lr)*40 + quad*8];
      #pragma unroll
      for (int no=0;no<3;no++){
        union { short8 v; unsigned short u[8]; } V;
        int col = wave*DH + no*16 + lr;
        int chunk = col >> 3;
        int cs = (chunk ^ (quad*2))*8 + (col & 7);
        #pragma unroll
        for (int j=0;j<8;j++){
          int key = c2*64 + ks*32 + quad*8 + j;
          V.u[j] = Vs[key*192 + cs];
        }
        #pragma unroll
        for (int mt=0;mt<2;mt++)
          o[mt][no] = __builtin_amdgcn_mfma_f32_16x16x32_bf16(pa[mt], V.v, o[mt][no], 0,0,0);
      }
    }
  }

  // ---- epilogue ----
  #pragma unroll
  for (int mt=0;mt<2;mt++){
    #pragma unroll
    for (int no=0;no<3;no++){
      int d = no*16 + lr;
      #pragma unroll
      for (int r=0;r<4;r++){
        int q = mt*16 + quad*4 + r;
        size_t grow = (size_t)(w*NQW + q);
        float g = bf2f(qh[grow*3072 + 2304 + h*DH + d]);
        og[grow*CA + h*DH + d] = f2bf(o[mt][no][r] * sigmoidf_(g));
      }
    }
  }
}

extern "C" void kernel_launch(void* const* d_in, const int* in_sizes, int n_in,
                              void* d_out, int out_size, void* d_ws, size_t ws_size,
                              hipStream_t stream)
{
  const float* a            = (const float*)d_in[0];
  const float* s            = (const float*)d_in[1];
  const float* z            = (const float*)d_in[2];
  const float* adaln_gamma  = (const float*)d_in[3];
  const float* adaln_ws     = (const float*)d_in[4];
  const float* adaln_bs     = (const float*)d_in[5];
  const float* adaln_wskip  = (const float*)d_in[6];
  const float* lnz_gamma    = (const float*)d_in[7];
  const float* wz           = (const float*)d_in[8];
  const float* wq           = (const float*)d_in[9];
  const float* bq           = (const float*)d_in[10];
  const float* wk           = (const float*)d_in[11];
  const float* wv           = (const float*)d_in[12];
  const float* wg           = (const float*)d_in[13];
  const float* bg           = (const float*)d_in[14];
  const float* wo           = (const float*)d_in[15];
  const float* bo           = (const float*)d_in[16];
  const float* w_last       = (const float*)d_in[17];
  const float* b_last       = (const float*)d_in[18];
  float* out = (float*)d_out;

  char* base = (char*)d_ws;
  size_t off = 0;
  auto alloc = [&](size_t bytes)->char*{ char* p = base + off; off += (bytes + 255) & ~(size_t)255; return p; };

  unsigned short* s_ln_h = (unsigned short*)alloc((size_t)N_TOK*CS*2);
  unsigned short* s_h    = (unsigned short*)alloc((size_t)N_TOK*CS*2);
  float*          a_n    = (float*)alloc((size_t)N_TOK*CA*4);
  unsigned short* a_ln_h = (unsigned short*)alloc((size_t)N_TOK*CA*2);
  unsigned short* og_h   = (unsigned short*)alloc((size_t)N_TOK*CA*2);
  unsigned short* Wt1    = (unsigned short*)alloc((size_t)1536*CS*2);
  unsigned short* Wt2    = (unsigned short*)alloc((size_t)3072*CA*2);
  unsigned short* Wt3    = (unsigned short*)alloc((size_t)CA*CA*2);
  unsigned short* Wt4    = (unsigned short*)alloc((size_t)CA*CS*2);
  unsigned short* bias3h = (unsigned short*)alloc((size_t)N_TOK*NHEAD*NKW*2);
  unsigned short* qkvg_h = (unsigned short*)alloc((size_t)N_TOK*3072*2);
  float*          biasq  = (float*)alloc((size_t)3072*4);

  prep_zbias_kernel<<<dim3(2048+1024+1024+936+12), 256, 0, stream>>>(
      z, lnz_gamma, wz, bias3h,
      s, adaln_gamma, s_ln_h, s_h, a, a_n,
      adaln_ws, adaln_wskip, wq, wk, wv, wg, wo, w_last,
      Wt1, Wt2, Wt3, Wt4, bq, bg, biasq);

  adaln_gemm<<<dim3(CA/128, N_TOK/64), 256, 0, stream>>>(s_ln_h, Wt1, adaln_bs, a_n, a_ln_h);

  qkvg_gemm<<<dim3(3072/128, N_TOK/128), 256, 0, stream>>>(a_ln_h, Wt2, biasq, qkvg_h);

  attn_kernel<<<dim3(NBLK, 4), 256, 0, stream>>>(qkvg_h, bias3h, og_h);

  final_gemm<<<dim3(CA/128, N_TOK/64), 256, 0, stream>>>(
      og_h, Wt3, bo, s_h, Wt4, b_last, out);
}

// Round 13
// 216.963 us; speedup vs baseline: 1.1649x; 1.0026x over previous
//
#include <hip/hip_runtime.h>
#include <hip/hip_bf16.h>
#include <math.h>

#define N_TOK 4096
#define CA 768
#define CS 384
#define CZ 128
#define NHEAD 16
#define DH 48
#define NQW 32
#define NKW 128
#define NBLK 128

typedef __attribute__((ext_vector_type(8))) short short8;
typedef __attribute__((ext_vector_type(4))) float float4v;
typedef __attribute__((ext_vector_type(4))) unsigned short ushort4v;

__device__ __forceinline__ float sigmoidf_(float x){ return 1.0f/(1.0f+__expf(-x)); }

__device__ __forceinline__ unsigned short f2bf(float x){
  unsigned u = __float_as_uint(x);
  unsigned r = (u + 0x7FFFu + ((u>>16)&1u)) >> 16;
  return (unsigned short)r;
}
__device__ __forceinline__ float bf2f(unsigned short b){
  return __uint_as_float(((unsigned)b)<<16);
}
__device__ __forceinline__ short8 cvt8(const float* xv){
  union { short8 v; unsigned short u[8]; } H;
  #pragma unroll
  for (int j=0;j<8;j++) H.u[j] = f2bf(xv[j]);
  return H.v;
}
// RNE pack via HW instruction (same bits as f2bf for finite inputs)
__device__ __forceinline__ short8 cvt8pk(const float* x){
  union { short8 v; unsigned u32[4]; } H;
  #pragma unroll
  for (int i=0;i<4;i++)
    asm("v_cvt_pk_bf16_f32 %0, %1, %2" : "=v"(H.u32[i]) : "v"(x[2*i]), "v"(x[2*i+1]));
  return H.v;
}

__device__ __forceinline__ void gload_lds16(const void* gsrc, void* ldst){
  __builtin_amdgcn_global_load_lds(
    (const __attribute__((address_space(1))) void*)gsrc,
    (__attribute__((address_space(3))) void*)ldst, 16, 0, 0);
}

// bijective XCD swizzle (nwg % 8 == 0)
__device__ __forceinline__ int xcd_swz(int wg, int nwg){
  int cpx = nwg >> 3;
  return (wg & 7)*cpx + (wg >> 3);
}

// ---------------- merged prep + zbias (32KB LDS union -> 5 blocks/CU) ----------------
// [0,2048): zbias (2 groups each, waves 0-1) ; +1024 ln_s ; +1024 ln_a ; +936 cvtT ; +12 biasq
__global__ __launch_bounds__(256) void prep_zbias_kernel(
  const float* __restrict__ z, const float* __restrict__ lnz_gamma,
  const float* __restrict__ wz, unsigned short* __restrict__ bias3,
  const float* __restrict__ s, const float* __restrict__ adaln_gamma,
  unsigned short* __restrict__ s_ln_h, unsigned short* __restrict__ s_h,
  const float* __restrict__ a, float* __restrict__ a_n,
  const float* __restrict__ ws, const float* __restrict__ wskip,
  const float* __restrict__ wq, const float* __restrict__ wk,
  const float* __restrict__ wv, const float* __restrict__ wg,
  const float* __restrict__ wo, const float* __restrict__ wlast,
  unsigned short* __restrict__ Wt1, unsigned short* __restrict__ Wt2,
  unsigned short* __restrict__ Wt3, unsigned short* __restrict__ Wt4,
  const float* __restrict__ bq, const float* __restrict__ bg,
  float* __restrict__ biasq)
{
  union PZ {
    float tile[64][65];       // 16.6 KB
    float zbuf[2][2][2048];   // 32 KB (2 zbias waves, dbuf)
  };
  __shared__ PZ sm;
  int bid = blockIdx.x;
  int tid = threadIdx.x;

  if (bid < 2048){
    // ================= zbias (waves 0,1 only) =================
    int wave = tid>>6, lane = tid&63;
    if (wave >= 2) return;
    int lr = lane&15, quad = lane>>4;

    short8 bwh[4];
    float w1 = 0.f;
    #pragma unroll
    for (int ks=0;ks<4;ks++){
      float wv_[8];
      #pragma unroll
      for (int j=0;j<8;j++){
        int k = ks*32 + quad*8 + j;
        wv_[j] = wz[k*NHEAD + lr]*lnz_gamma[k];
        w1 += wv_[j];
      }
      bwh[ks] = cvt8pk(wv_);
    }
    w1 += __shfl_xor(w1, 16);
    w1 += __shfl_xor(w1, 32);

    size_t group = (size_t)bid*2 + wave;   // 0..4095
    const float* zg = z + group*(size_t)(NKW*CZ);
    unsigned short* outg = bias3 + group*2048;

    int rsub = lane>>5;
    int csw  = lane&31;
    auto stage = [&](int buf, int b){
      #pragma unroll
      for (int i=0;i<8;i++){
        int r  = 2*i + rsub;
        int gc = csw ^ (r & 7);
        gload_lds16(zg + (size_t)(b*16 + r)*CZ + gc*4, &sm.zbuf[wave][buf][i*256]);
      }
    };

    stage(0, 0);
    int buf = 0;
    #pragma unroll 1
    for (int b=0; b<8; ++b){
      if (b < 7){
        stage(buf^1, b+1);
        asm volatile("s_waitcnt vmcnt(8)" ::: "memory");
      } else {
        asm volatile("s_waitcnt vmcnt(0)" ::: "memory");
      }
      __builtin_amdgcn_sched_barrier(0);

      const float* rowp = &sm.zbuf[wave][buf][lr*128];
      int sswz = lr & 7;
      float4 p[8];
      #pragma unroll
      for (int ks=0;ks<4;ks++){
        int c0 = ks*8 + quad*2;
        p[ks*2]   = *(const float4*)(rowp + (size_t)((c0  )^sswz)*4);
        p[ks*2+1] = *(const float4*)(rowp + (size_t)((c0+1)^sswz)*4);
      }
      float sum=0.f, sq=0.f;
      #pragma unroll
      for (int t=0;t<8;t++){
        sum += p[t].x + p[t].y + p[t].z + p[t].w;
        sq  += p[t].x*p[t].x + p[t].y*p[t].y + p[t].z*p[t].z + p[t].w*p[t].w;
      }
      sum += __shfl_xor(sum,16); sum += __shfl_xor(sum,32);
      sq  += __shfl_xor(sq,16);  sq  += __shfl_xor(sq,32);
      float mean = sum*(1.f/CZ);
      float var  = sq*(1.f/CZ) - mean*mean;
      float rs = rsqrtf(var + 1e-5f);

      float4v c = (float4v){0.f,0.f,0.f,0.f};
      #pragma unroll
      for (int ks=0;ks<4;ks++){
        float xv[8];
        xv[0]=p[ks*2].x;   xv[1]=p[ks*2].y;   xv[2]=p[ks*2].z;   xv[3]=p[ks*2].w;
        xv[4]=p[ks*2+1].x; xv[5]=p[ks*2+1].y; xv[6]=p[ks*2+1].z; xv[7]=p[ks*2+1].w;
        c = __builtin_amdgcn_mfma_f32_16x16x32_bf16(cvt8pk(xv), bwh[ks], c, 0,0,0);
      }

      ushort4v o4;
      #pragma unroll
      for (int r=0;r<4;r++){
        int rrow = quad*4 + r;
        float m_r  = __shfl(mean, rrow);
        float rs_r = __shfl(rs, rrow);
        o4[r] = f2bf(rs_r*(c[r] - m_r*w1));
      }
      *(ushort4v*)(outg + lr*128 + b*16 + quad*4) = o4;
      buf ^= 1;
    }
    return;
  }
  bid -= 2048;

  if (bid < 1024){
    // ================= ln_s =================
    int wave = tid>>6, lane = tid&63;
    int row = bid*4 + wave;
    const float* x = s + (size_t)row*CS;
    float v[6]; float sum=0.f, sq=0.f;
    #pragma unroll
    for (int i=0;i<6;i++){ v[i]=x[lane+64*i]; sum+=v[i]; sq+=v[i]*v[i]; }
    #pragma unroll
    for (int off=32; off; off>>=1){ sum+=__shfl_xor(sum,off); sq+=__shfl_xor(sq,off); }
    float m = sum*(1.f/CS);
    float var = sq*(1.f/CS)-m*m;
    float rs = rsqrtf(var+1e-5f);
    #pragma unroll
    for (int i=0;i<6;i++){
      int c = lane+64*i;
      s_ln_h[(size_t)row*CS+c] = f2bf((v[i]-m)*rs*adaln_gamma[c]);
      s_h[(size_t)row*CS+c]    = f2bf(v[i]);
    }
    return;
  }
  bid -= 1024;

  if (bid < 1024){
    // ================= ln_a =================
    int wave = tid>>6, lane = tid&63;
    int row = bid*4 + wave;
    const float* x = a + (size_t)row*CA;
    float v[12]; float sum=0.f, sq=0.f;
    #pragma unroll
    for (int i=0;i<12;i++){ v[i]=x[lane+64*i]; sum+=v[i]; sq+=v[i]*v[i]; }
    #pragma unroll
    for (int off=32; off; off>>=1){ sum+=__shfl_xor(sum,off); sq+=__shfl_xor(sq,off); }
    float m = sum*(1.f/CA);
    float var = sq*(1.f/CA)-m*m;
    float rs = rsqrtf(var+1e-5f);
    float* o = a_n + (size_t)row*CA;
    #pragma unroll
    for (int i=0;i<12;i++) o[lane+64*i] = (v[i]-m)*rs;
    return;
  }
  bid -= 1024;

  if (bid < 936){
    // ================= weight transpose+cvt =================
    const float* src; unsigned short* dst; int K; int local;
    if      (bid < 72)  { src=ws;    dst=Wt1;                   K=CS; local=bid; }
    else if (bid < 144) { src=wskip; dst=Wt1 + (size_t)768*CS;  K=CS; local=bid-72; }
    else if (bid < 288) { src=wq;    dst=Wt2;                   K=CA; local=bid-144; }
    else if (bid < 432) { src=wk;    dst=Wt2 + (size_t)768*CA;  K=CA; local=bid-288; }
    else if (bid < 576) { src=wv;    dst=Wt2 + (size_t)1536*CA; K=CA; local=bid-432; }
    else if (bid < 720) { src=wg;    dst=Wt2 + (size_t)2304*CA; K=CA; local=bid-576; }
    else if (bid < 864) { src=wo;    dst=Wt3;                   K=CA; local=bid-720; }
    else                { src=wlast; dst=Wt4;                   K=CS; local=bid-864; }
    int ktiles = K/64;
    int kb = (local % ktiles)*64, nb = (local / ktiles)*64;
    int c = tid & 63, r0 = tid >> 6;
    #pragma unroll
    for (int i=0;i<16;i++){
      int r = r0 + 4*i;
      sm.tile[r][c] = src[(size_t)(kb+r)*CA + nb + c];
    }
    __syncthreads();
    #pragma unroll
    for (int i=0;i<16;i++){
      int r = r0 + 4*i;          // n-local
      dst[(size_t)(nb+r)*K + kb + c] = f2bf(sm.tile[c][r]);
    }
    return;
  }
  bid -= 936;

  // ================= biasq =================
  int i = bid*256 + tid;
  float v = 0.f;
  if (i < 768) v = bq[i];
  else if (i >= 2304) v = bg[i-2304];
  biasq[i] = v;
}

// ---------------- adaln GEMM, 64x128 tile, BK=64 + XOR chunk swizzle ----------------
// a_ln = sigmoid(s_ln@ws + bs)*a_n + s_ln@wskip -> bf16
__global__ __launch_bounds__(256) void adaln_gemm(
  const unsigned short* __restrict__ A, const unsigned short* __restrict__ Bt,
  const float* __restrict__ bs, const float* __restrict__ a_n,
  unsigned short* __restrict__ outh)
{
  __shared__ unsigned short Ash[64*64];
  __shared__ unsigned short B1sh[128*64];
  __shared__ unsigned short B2sh[128*64];

  int tid = threadIdx.x;
  int w = tid >> 6, lane = tid & 63;
  int lr = lane & 15, quad = lane >> 4;
  int wg = xcd_swz(blockIdx.y*gridDim.x + blockIdx.x, gridDim.x*gridDim.y);
  int bx = wg % gridDim.x, by = wg / gridDim.x;
  int m0 = by*64, n0 = bx*128;
  int mbase = (w&1)*32, nbase = (w>>1)*64;

  float4v acc1[2][4], acc2[2][4];
  #pragma unroll
  for (int i=0;i<2;i++)
    #pragma unroll
    for (int j=0;j<4;j++){
      acc1[i][j] = (float4v){0.f,0.f,0.f,0.f};
      acc2[i][j] = (float4v){0.f,0.f,0.f,0.f};
    }

  int rsub = lane>>3;              // row within 8-row issue (0..7)
  int gcs  = ((lane&7) ^ rsub)*8;  // swizzled source chunk (ushorts)
  int rkey = lr & 7;               // read-side XOR key

  for (int k0=0; k0<CS; k0+=64){
    __syncthreads();
    #pragma unroll
    for (int it=0; it<2; ++it){    // A: 64 rows
      int r = it*32 + w*8 + rsub;
      gload_lds16(A + (size_t)(m0 + r)*CS + k0 + gcs, &Ash[(it*32 + w*8)*64]);
    }
    #pragma unroll
    for (int it=0; it<4; ++it){    // B1,B2: 128 rows each
      int r = it*32 + w*8 + rsub;
      gload_lds16(Bt + (size_t)(n0 + r)*CS + k0 + gcs, &B1sh[(it*32 + w*8)*64]);
      gload_lds16(Bt + (size_t)(768 + n0 + r)*CS + k0 + gcs, &B2sh[(it*32 + w*8)*64]);
    }
    __syncthreads();

    #pragma unroll
    for (int ks=0; ks<2; ++ks){
      int slot = ((ks*4 + quad) ^ rkey)*8;
      short8 af[2], b1f[4], b2f[4];
      #pragma unroll
      for (int mi=0;mi<2;mi++)
        af[mi] = *(const short8*)&Ash[(mbase + mi*16 + lr)*64 + slot];
      #pragma unroll
      for (int ni=0;ni<4;ni++){
        b1f[ni] = *(const short8*)&B1sh[(nbase + ni*16 + lr)*64 + slot];
        b2f[ni] = *(const short8*)&B2sh[(nbase + ni*16 + lr)*64 + slot];
      }
      #pragma unroll
      for (int mi=0;mi<2;mi++)
        #pragma unroll
        for (int ni=0;ni<4;ni++){
          acc1[mi][ni] = __builtin_amdgcn_mfma_f32_16x16x32_bf16(af[mi], b1f[ni], acc1[mi][ni], 0,0,0);
          acc2[mi][ni] = __builtin_amdgcn_mfma_f32_16x16x32_bf16(af[mi], b2f[ni], acc2[mi][ni], 0,0,0);
        }
    }
  }

  #pragma unroll
  for (int ni=0;ni<4;ni++){
    int col = n0 + nbase + ni*16 + lr;
    float bsv = bs[col];
    #pragma unroll
    for (int mi=0;mi<2;mi++){
      #pragma unroll
      for (int reg=0;reg<4;reg++){
        int row = m0 + mbase + mi*16 + quad*4 + reg;
        float v = sigmoidf_(acc1[mi][ni][reg] + bsv)*a_n[(size_t)row*CA + col] + acc2[mi][ni][reg];
        outh[(size_t)row*CA + col] = f2bf(v);
      }
    }
  }
}

// ---------------- final dual-K GEMM, 64x128 tile, BK=64 + XOR chunk swizzle ----------------
// out = sigmoid(s@wlast+blast) * (og@wo+bo)  (f32 out)
__global__ __launch_bounds__(256) void final_gemm(
  const unsigned short* __restrict__ A1, const unsigned short* __restrict__ B1,
  const float* __restrict__ bias1,
  const unsigned short* __restrict__ A2, const unsigned short* __restrict__ B2,
  const float* __restrict__ bias2,
  float* __restrict__ outp)
{
  __shared__ unsigned short Ash[64*64];
  __shared__ unsigned short Bsh[128*64];

  int tid = threadIdx.x;
  int w = tid >> 6, lane = tid & 63;
  int lr = lane & 15, quad = lane >> 4;
  int wg = xcd_swz(blockIdx.y*gridDim.x + blockIdx.x, gridDim.x*gridDim.y);
  int bx = wg % gridDim.x, by = wg / gridDim.x;
  int m0 = by*64, n0 = bx*128;
  int mbase = (w&1)*32, nbase = (w>>1)*64;

  float4v acc1[2][4], acc2[2][4];
  #pragma unroll
  for (int i=0;i<2;i++)
    #pragma unroll
    for (int j=0;j<4;j++){
      acc1[i][j] = (float4v){0.f,0.f,0.f,0.f};
      acc2[i][j] = (float4v){0.f,0.f,0.f,0.f};
    }

  int rsub = lane>>3;
  int gcs  = ((lane&7) ^ rsub)*8;
  int rkey = lr & 7;

  const int NT1 = CA/64, NT2 = CS/64, NT = NT1+NT2;  // 12+6
  #pragma unroll 1
  for (int t=0; t<NT; ++t){
    const unsigned short* Ap; const unsigned short* Bp; int K, k0;
    if (t < NT1){ Ap=A1; Bp=B1; K=CA; k0=t*64; }
    else        { Ap=A2; Bp=B2; K=CS; k0=(t-NT1)*64; }
    __syncthreads();
    #pragma unroll
    for (int it=0; it<2; ++it){
      int r = it*32 + w*8 + rsub;
      gload_lds16(Ap + (size_t)(m0 + r)*K + k0 + gcs, &Ash[(it*32 + w*8)*64]);
    }
    #pragma unroll
    for (int it=0; it<4; ++it){
      int r = it*32 + w*8 + rsub;
      gload_lds16(Bp + (size_t)(n0 + r)*K + k0 + gcs, &Bsh[(it*32 + w*8)*64]);
    }
    __syncthreads();

    #pragma unroll
    for (int ks=0; ks<2; ++ks){
      int slot = ((ks*4 + quad) ^ rkey)*8;
      short8 af[2], bf[4];
      #pragma unroll
      for (int mi=0;mi<2;mi++)
        af[mi] = *(const short8*)&Ash[(mbase + mi*16 + lr)*64 + slot];
      #pragma unroll
      for (int ni=0;ni<4;ni++)
        bf[ni] = *(const short8*)&Bsh[(nbase + ni*16 + lr)*64 + slot];
      if (t < NT1){
        #pragma unroll
        for (int mi=0;mi<2;mi++)
          #pragma unroll
          for (int ni=0;ni<4;ni++)
            acc1[mi][ni] = __builtin_amdgcn_mfma_f32_16x16x32_bf16(af[mi], bf[ni], acc1[mi][ni], 0,0,0);
      } else {
        #pragma unroll
        for (int mi=0;mi<2;mi++)
          #pragma unroll
          for (int ni=0;ni<4;ni++)
            acc2[mi][ni] = __builtin_amdgcn_mfma_f32_16x16x32_bf16(af[mi], bf[ni], acc2[mi][ni], 0,0,0);
      }
    }
  }

  #pragma unroll
  for (int ni=0;ni<4;ni++){
    int col = n0 + nbase + ni*16 + lr;
    float bv1 = bias1[col];
    float bv2 = bias2[col];
    #pragma unroll
    for (int mi=0;mi<2;mi++){
      #pragma unroll
      for (int reg=0;reg<4;reg++){
        int row = m0 + mbase + mi*16 + quad*4 + reg;
        outp[(size_t)row*CA + col] = sigmoidf_(acc2[mi][ni][reg] + bv2)*(acc1[mi][ni][reg] + bv1);
      }
    }
  }
}

// ---------------- qkvg GEMM: 256x256 tile, 8 waves, counted-vmcnt dbuf pipeline ----------------
// grid (12,16) = 192 blocks; LDS 128KB; vmcnt never drained to 0 in steady state
__global__ __launch_bounds__(512) void qkvg_gemm256(
  const unsigned short* __restrict__ A1, const unsigned short* __restrict__ B1,
  const float* __restrict__ bias1, unsigned short* __restrict__ outp)
{
  __shared__ unsigned short Ash[2][256*64];
  __shared__ unsigned short Bsh[2][256*64];

  int tid = threadIdx.x;
  int v = tid >> 6, lane = tid & 63;
  int lr = lane & 15, quad = lane >> 4;
  int wg = xcd_swz(blockIdx.y*gridDim.x + blockIdx.x, gridDim.x*gridDim.y);
  int bx = wg % gridDim.x, by = wg / gridDim.x;
  int m0 = by*256, n0 = bx*256;
  int wr = (v>>2)*128;     // wave m-offset (0 or 128)
  int wc = (v&3)*64;       // wave n-offset (0,64,128,192)

  float4v acc[8][4];
  #pragma unroll
  for (int i=0;i<8;i++)
    #pragma unroll
    for (int j=0;j<4;j++)
      acc[i][j] = (float4v){0.f,0.f,0.f,0.f};

  int rsub = lane>>3;              // row within 8-row issue
  int gcs  = ((lane&7) ^ rsub)*8;  // swizzled source chunk (ushorts)
  int rkey = lr & 7;

  const int NT = CA/64;  // 12

  auto stage = [&](int buf, int t){
    int k0 = t*64;
    #pragma unroll
    for (int i=0;i<4;i++){
      int R = i*64 + v*8;          // multiple of 8; covers 256 rows across 8 waves
      gload_lds16(A1 + (size_t)(m0 + R + rsub)*CA + k0 + gcs, &Ash[buf][R*64]);
      gload_lds16(B1 + (size_t)(n0 + R + rsub)*CA + k0 + gcs, &Bsh[buf][R*64]);
    }
  };

  // prologue: 2 tiles in flight
  stage(0, 0);
  stage(1, 1);
  int cur = 0;
  #pragma unroll 1
  for (int t=0; t<NT; ++t){
    if (t+1 < NT) asm volatile("s_waitcnt vmcnt(8)" ::: "memory");   // own tile-t loads landed
    else          asm volatile("s_waitcnt vmcnt(0)" ::: "memory");
    __builtin_amdgcn_sched_barrier(0);
    __builtin_amdgcn_s_barrier();          // everyone's tile-t loads landed
    #pragma unroll
    for (int ks=0; ks<2; ++ks){
      int slot = ((ks*4 + quad) ^ rkey)*8;
      short8 af[8], bf[4];
      #pragma unroll
      for (int mi=0;mi<8;mi++)
        af[mi] = *(const short8*)&Ash[cur][(wr + mi*16 + lr)*64 + slot];
      #pragma unroll
      for (int ni=0;ni<4;ni++)
        bf[ni] = *(const short8*)&Bsh[cur][(wc + ni*16 + lr)*64 + slot];
      #pragma unroll
      for (int mi=0;mi<8;mi++)
        #pragma unroll
        for (int ni=0;ni<4;ni++)
          acc[mi][ni] = __builtin_amdgcn_mfma_f32_16x16x32_bf16(af[mi], bf[ni], acc[mi][ni], 0,0,0);
    }
    __builtin_amdgcn_s_barrier();          // all waves done reading buf[cur]
    if (t+2 < NT) stage(cur, t+2);         // refill just-freed buffer
    cur ^= 1;
  }

  #pragma unroll
  for (int ni=0;ni<4;ni++){
    int col = n0 + wc + ni*16 + lr;
    float bv = bias1[col];
    #pragma unroll
    for (int mi=0;mi<8;mi++){
      #pragma unroll
      for (int reg=0;reg<4;reg++){
        int row = m0 + wr + mi*16 + quad*4 + reg;
        outp[(size_t)row*3072 + col] = f2bf(acc[mi][ni][reg] + bv);
      }
    }
  }
}

// ---------------- attention: one wave per (w,h); V staged in LDS ----------------
__global__ __launch_bounds__(256) void attn_kernel(
  const unsigned short* __restrict__ qh,
  const unsigned short* __restrict__ bias3h,
  unsigned short* __restrict__ og)
{
  __shared__ unsigned short Vs[128*192];
  __shared__ unsigned short Pb[4][32*40];
  int tid = threadIdx.x, wave = tid>>6, lane = tid&63;
  int lr = lane&15, quad = lane>>4;
  int w = blockIdx.x, h = blockIdx.y*4 + wave;
  int start = w*NQW - 48;
  const float scale = 0.14433756729740643f;  // 1/sqrt(48)

  // ---- cooperative V staging ----
  {
    int hbase = blockIdx.y*4*DH;
    #pragma unroll
    for (int it=0; it<12; ++it){
      int c = it*256 + tid;
      int key = c/24, cc = c - key*24;
      int kr = min(max(start+key,0),N_TOK-1);
      short8 v = *(const short8*)&qh[(size_t)kr*3072 + 1536 + hbase + cc*8];
      int cs = cc ^ (((key>>3)&3)*2);
      *(short8*)&Vs[key*192 + cs*8] = v;
    }
  }

  short8 zero8 = {0,0,0,0,0,0,0,0};

  // ---- Q A-frags ----
  short8 aq[2][2];
  #pragma unroll
  for (int mt=0;mt<2;mt++){
    int row = w*NQW + mt*16 + lr;
    const unsigned short* qp = qh + (size_t)row*3072 + h*DH;
    aq[mt][0] = *(const short8*)(qp + quad*8);
    aq[mt][1] = (quad<2) ? *(const short8*)(qp + 32 + quad*8) : zero8;
  }

  // ---- QK^T ----
  float4v c[2][8];
  #pragma unroll
  for (int mt=0;mt<2;mt++)
    #pragma unroll
    for (int nt=0;nt<8;nt++) c[mt][nt] = (float4v){0.f,0.f,0.f,0.f};

  #pragma unroll 2
  for (int nt=0;nt<8;nt++){
    int krc = min(max(start + nt*16 + lr,0),N_TOK-1);
    const unsigned short* kp = qh + (size_t)krc*3072 + 768 + h*DH;
    short8 bk0 = *(const short8*)(kp + quad*8);
    short8 bk1 = (quad<2) ? *(const short8*)(kp + 32 + quad*8) : zero8;
    #pragma unroll
    for (int mt=0;mt<2;mt++){
      c[mt][nt] = __builtin_amdgcn_mfma_f32_16x16x32_bf16(aq[mt][0], bk0, c[mt][nt], 0,0,0);
      c[mt][nt] = __builtin_amdgcn_mfma_f32_16x16x32_bf16(aq[mt][1], bk1, c[mt][nt], 0,0,0);
    }
  }

  // ---- bias + mask + softmax in registers ----
  float rmax[2][4], rsum[2][4];
  #pragma unroll
  for (int mt=0;mt<2;mt++)
    #pragma unroll
    for (int r=0;r<4;r++){ rmax[mt][r] = -3.0e38f; rsum[mt][r] = 0.f; }

  #pragma unroll
  for (int nt=0;nt<8;nt++){
    int key = start + nt*16 + lr;
    bool valid = (key>=0) && (key<N_TOK);
    #pragma unroll
    for (int mt=0;mt<2;mt++){
      #pragma unroll
      for (int r=0;r<4;r++){
        int q = mt*16 + quad*4 + r;
        float bv = bf2f(bias3h[(((size_t)(w*NQW+q))*NHEAD + h)*128 + nt*16 + lr]);
        float v = valid ? (c[mt][nt][r]*scale + bv) : -1e9f;
        c[mt][nt][r] = v;
        rmax[mt][r] = fmaxf(rmax[mt][r], v);
      }
    }
  }
  #pragma unroll
  for (int mt=0;mt<2;mt++)
    #pragma unroll
    for (int r=0;r<4;r++){
      float m = rmax[mt][r];
      m = fmaxf(m, __shfl_xor(m,1)); m = fmaxf(m, __shfl_xor(m,2));
      m = fmaxf(m, __shfl_xor(m,4)); m = fmaxf(m, __shfl_xor(m,8));
      rmax[mt][r] = m;
    }
  #pragma unroll
  for (int nt=0;nt<8;nt++)
    #pragma unroll
    for (int mt=0;mt<2;mt++)
      #pragma unroll
      for (int r=0;r<4;r++){
        float e = __expf(c[mt][nt][r] - rmax[mt][r]);
        c[mt][nt][r] = e;
        rsum[mt][r] += e;
      }
  #pragma unroll
  for (int mt=0;mt<2;mt++)
    #pragma unroll
    for (int r=0;r<4;r++){
      float sv = rsum[mt][r];
      sv += __shfl_xor(sv,1); sv += __shfl_xor(sv,2);
      sv += __shfl_xor(sv,4); sv += __shfl_xor(sv,8);
      rsum[mt][r] = 1.f/sv;
    }

  __syncthreads();   // Vs staged by all waves

  // ---- PV ----
  unsigned short* ph = &Pb[wave][0];
  float4v o[2][3];
  #pragma unroll
  for (int mt=0;mt<2;mt++)
    #pragma unroll
    for (int no=0;no<3;no++) o[mt][no] = (float4v){0.f,0.f,0.f,0.f};

  #pragma unroll 1
  for (int c2=0;c2<2;c2++){
    #pragma unroll 1
    for (int ks=0;ks<2;ks++){
      int ntb = c2*4 + ks*2;
      #pragma unroll
      for (int t=0;t<2;t++){
        int nt = ntb + t;
        #pragma unroll
        for (int mt=0;mt<2;mt++){
          #pragma unroll
          for (int r=0;r<4;r++){
            int q = mt*16 + quad*4 + r;
            ph[q*40 + t*16 + lr] = f2bf(c[mt][nt][r]*rsum[mt][r]);
          }
        }
      }
      short8 pa[2];
      #pragma unroll
      for (int mt=0;mt<2;mt++)
        pa[mt] = *(const short8*)&ph[(mt*16+lr)*40 + quad*8];
      #pragma unroll
      for (int no=0;no<3;no++){
        union { short8 v; unsigned short u[8]; } V;
        int col = wave*DH + no*16 + lr;
        int chunk = col >> 3;
        int cs = (chunk ^ (quad*2))*8 + (col & 7);
        #pragma unroll
        for (int j=0;j<8;j++){
          int key = c2*64 + ks*32 + quad*8 + j;
          V.u[j] = Vs[key*192 + cs];
        }
        #pragma unroll
        for (int mt=0;mt<2;mt++)
          o[mt][no] = __builtin_amdgcn_mfma_f32_16x16x32_bf16(pa[mt], V.v, o[mt][no], 0,0,0);
      }
    }
  }

  // ---- epilogue ----
  #pragma unroll
  for (int mt=0;mt<2;mt++){
    #pragma unroll
    for (int no=0;no<3;no++){
      int d = no*16 + lr;
      #pragma unroll
      for (int r=0;r<4;r++){
        int q = mt*16 + quad*4 + r;
        size_t grow = (size_t)(w*NQW + q);
        float g = bf2f(qh[grow*3072 + 2304 + h*DH + d]);
        og[grow*CA + h*DH + d] = f2bf(o[mt][no][r] * sigmoidf_(g));
      }
    }
  }
}

extern "C" void kernel_launch(void* const* d_in, const int* in_sizes, int n_in,
                              void* d_out, int out_size, void* d_ws, size_t ws_size,
                              hipStream_t stream)
{
  const float* a            = (const float*)d_in[0];
  const float* s            = (const float*)d_in[1];
  const float* z            = (const float*)d_in[2];
  const float* adaln_gamma  = (const float*)d_in[3];
  const float* adaln_ws     = (const float*)d_in[4];
  const float* adaln_bs     = (const float*)d_in[5];
  const float* adaln_wskip  = (const float*)d_in[6];
  const float* lnz_gamma    = (const float*)d_in[7];
  const float* wz           = (const float*)d_in[8];
  const float* wq           = (const float*)d_in[9];
  const float* bq           = (const float*)d_in[10];
  const float* wk           = (const float*)d_in[11];
  const float* wv           = (const float*)d_in[12];
  const float* wg           = (const float*)d_in[13];
  const float* bg           = (const float*)d_in[14];
  const float* wo           = (const float*)d_in[15];
  const float* bo           = (const float*)d_in[16];
  const float* w_last       = (const float*)d_in[17];
  const float* b_last       = (const float*)d_in[18];
  float* out = (float*)d_out;

  char* base = (char*)d_ws;
  size_t off = 0;
  auto alloc = [&](size_t bytes)->char*{ char* p = base + off; off += (bytes + 255) & ~(size_t)255; return p; };

  unsigned short* s_ln_h = (unsigned short*)alloc((size_t)N_TOK*CS*2);
  unsigned short* s_h    = (unsigned short*)alloc((size_t)N_TOK*CS*2);
  float*          a_n    = (float*)alloc((size_t)N_TOK*CA*4);
  unsigned short* a_ln_h = (unsigned short*)alloc((size_t)N_TOK*CA*2);
  unsigned short* og_h   = (unsigned short*)alloc((size_t)N_TOK*CA*2);
  unsigned short* Wt1    = (unsigned short*)alloc((size_t)1536*CS*2);
  unsigned short* Wt2    = (unsigned short*)alloc((size_t)3072*CA*2);
  unsigned short* Wt3    = (unsigned short*)alloc((size_t)CA*CA*2);
  unsigned short* Wt4    = (unsigned short*)alloc((size_t)CA*CS*2);
  unsigned short* bias3h = (unsigned short*)alloc((size_t)N_TOK*NHEAD*NKW*2);
  unsigned short* qkvg_h = (unsigned short*)alloc((size_t)N_TOK*3072*2);
  float*          biasq  = (float*)alloc((size_t)3072*4);

  prep_zbias_kernel<<<dim3(2048+1024+1024+936+12), 256, 0, stream>>>(
      z, lnz_gamma, wz, bias3h,
      s, adaln_gamma, s_ln_h, s_h, a, a_n,
      adaln_ws, adaln_wskip, wq, wk, wv, wg, wo, w_last,
      Wt1, Wt2, Wt3, Wt4, bq, bg, biasq);

  adaln_gemm<<<dim3(CA/128, N_TOK/64), 256, 0, stream>>>(s_ln_h, Wt1, adaln_bs, a_n, a_ln_h);

  qkvg_gemm256<<<dim3(3072/256, N_TOK/256), 512, 0, stream>>>(a_ln_h, Wt2, biasq, qkvg_h);

  attn_kernel<<<dim3(NBLK, 4), 256, 0, stream>>>(qkvg_h, bias3h, og_h);

  final_gemm<<<dim3(CA/128, N_TOK/64), 256, 0, stream>>>(
      og_h, Wt3, bo, s_h, Wt4, b_last, out);
}